// Round 2
// baseline (498.181 us; speedup 1.0000x reference)
//
#include <hip/hip_runtime.h>
#include <hip/hip_bf16.h>

#define D_MODEL 1024
#define T_SEQ   2048
#define BATCH   4
#define NHEADS  16
#define HDIM    64
#define M_ROWS  (BATCH * T_SEQ)   // 8192

typedef unsigned short ushortT;
typedef __attribute__((ext_vector_type(4))) float f32x4;
typedef __attribute__((ext_vector_type(8))) short s16x8;

#define GP(p) ((const __attribute__((address_space(1))) void*)(p))
#define LP(p) ((__attribute__((address_space(3))) void*)(p))

static __device__ __forceinline__ ushortT f2b(float f) {
    union { float f; unsigned u; } v; v.f = f;
    unsigned r = v.u + 0x7fffu + ((v.u >> 16) & 1u);
    return (ushortT)(r >> 16);
}

// ---------------- cast fp32 -> bf16, 8 elems/thread ----------------
__global__ void cast_f32_bf16(const float* __restrict__ src, ushortT* __restrict__ dst, int n8) {
    int i = blockIdx.x * 256 + threadIdx.x;
    if (i >= n8) return;
    const float4* s = (const float4*)src;
    float4 a = s[i * 2], b = s[i * 2 + 1];
    s16x8 r;
    r[0] = f2b(a.x); r[1] = f2b(a.y); r[2] = f2b(a.z); r[3] = f2b(a.w);
    r[4] = f2b(b.x); r[5] = f2b(b.y); r[6] = f2b(b.z); r[7] = f2b(b.w);
    ((s16x8*)dst)[i] = r;
}

// ---------------- GEMM: C[M,N] = A[M,K] * W[N,K]^T + bias ----------------
// modes: 0 = Q -> (BH,T,64) bf16 (scale 1/8 folded), 1 = K -> (BH,T,64) bf16,
//        2 = V -> (BH,64,T) bf16 (transposed), 3 = fp32 row-major to d_out.
__global__ __launch_bounds__(256, 2) void gemm_bt(
    const ushortT* __restrict__ A,
    const ushortT* __restrict__ Bw,
    const float*   __restrict__ bias,
    void*          __restrict__ outp,
    float scale, int mode)
{
    __shared__ __attribute__((aligned(16))) ushortT As[128 * 32];
    __shared__ __attribute__((aligned(16))) ushortT Bs[128 * 32];

    const int tid  = threadIdx.x;
    const int wave = tid >> 6, lane = tid & 63;
    const int wm = wave >> 1, wn = wave & 1;
    const int lr = lane & 15, lh = lane >> 4;
    const int m0 = blockIdx.x * 128, n0 = blockIdx.y * 128;

    const int srow = tid >> 2;        // 0..63
    const int sk   = (tid & 3) * 8;   // 0,8,16,24  (elements)

    f32x4 acc[4][4] = {};

    const ushortT* Ag = A  + (size_t)(m0 + srow) * 1024 + sk;
    const ushortT* Bg = Bw + (size_t)(n0 + srow) * 1024 + sk;
    ushortT* Al = As + srow * 32 + sk;   // byte off = tid*16
    ushortT* Bl = Bs + srow * 32 + sk;

    for (int k0 = 0; k0 < 1024; k0 += 32) {
        __builtin_amdgcn_global_load_lds(GP(Ag + k0),             LP(Al),           16, 0, 0);
        __builtin_amdgcn_global_load_lds(GP(Ag + 64 * 1024 + k0), LP(Al + 64 * 32), 16, 0, 0);
        __builtin_amdgcn_global_load_lds(GP(Bg + k0),             LP(Bl),           16, 0, 0);
        __builtin_amdgcn_global_load_lds(GP(Bg + 64 * 1024 + k0), LP(Bl + 64 * 32), 16, 0, 0);
        __syncthreads();

        s16x8 af[4], bfr[4];
        #pragma unroll
        for (int i = 0; i < 4; ++i)
            af[i] = *(const s16x8*)&As[(wm * 64 + i * 16 + lr) * 32 + lh * 8];
        #pragma unroll
        for (int j = 0; j < 4; ++j)
            bfr[j] = *(const s16x8*)&Bs[(wn * 64 + j * 16 + lr) * 32 + lh * 8];
        #pragma unroll
        for (int i = 0; i < 4; ++i)
            #pragma unroll
            for (int j = 0; j < 4; ++j)
                acc[i][j] = __builtin_amdgcn_mfma_f32_16x16x32_bf16(af[i], bfr[j], acc[i][j], 0, 0, 0);
        __syncthreads();
    }

    #pragma unroll
    for (int i = 0; i < 4; ++i) {
        #pragma unroll
        for (int j = 0; j < 4; ++j) {
            const int c = n0 + wn * 64 + j * 16 + lr;
            const float bv = bias[c];
            #pragma unroll
            for (int e = 0; e < 4; ++e) {
                const int r = m0 + wm * 64 + i * 16 + lh * 4 + e;
                const float val = (acc[i][j][e] + bv) * scale;
                if (mode == 3) {
                    ((float*)outp)[(size_t)r * 1024 + c] = val;
                } else {
                    const int b = r >> 11, t = r & 2047;
                    const int h = c >> 6,  d = c & 63;
                    size_t idx;
                    if (mode == 2) idx = ((size_t)(b * NHEADS + h) * HDIM + d) * T_SEQ + t;
                    else           idx = ((size_t)(b * NHEADS + h) * T_SEQ + t) * HDIM + d;
                    ((ushortT*)outp)[idx] = f2b(val);
                }
            }
        }
    }
}

// ---------------- flash attention, causal ----------------
// grid (T/64, B*H).  Q: (BH,T,64) bf16 pre-scaled by 1/8.  K: (BH,T,64).  Vt: (BH,64,T).
// Ob out: (B,T,D) bf16.
__global__ __launch_bounds__(256, 2) void attn_fwd(
    const ushortT* __restrict__ Qb, const ushortT* __restrict__ Kb,
    const ushortT* __restrict__ Vt, ushortT* __restrict__ Ob)
{
    __shared__ __attribute__((aligned(16))) ushortT Ks[64 * 64];
    __shared__ __attribute__((aligned(16))) ushortT Vs[64 * 64];
    __shared__ __attribute__((aligned(16))) ushortT Ps[4][16 * 64];

    const int tid = threadIdx.x;
    const int w = tid >> 6, lane = tid & 63;
    const int lr = lane & 15, lh = lane >> 4;
    const int qt = blockIdx.x, bh = blockIdx.y;
    const int q0 = qt * 64;

    // Q fragments (A operand): row = q0 + w*16 + lr, k = {0..31, 32..63}
    const ushortT* qrow = Qb + ((size_t)bh * T_SEQ + q0 + w * 16 + lr) * HDIM;
    const s16x8 qf0 = *(const s16x8*)(qrow + lh * 8);
    const s16x8 qf1 = *(const s16x8*)(qrow + 32 + lh * 8);

    float m_s[4], l_s[4];
    f32x4 o[4] = {};
    #pragma unroll
    for (int e = 0; e < 4; ++e) { m_s[e] = -1e30f; l_s[e] = 0.f; }

    const int srow = tid >> 3;       // 0..31
    const int sk   = (tid & 7) * 8;  // 0..56

    for (int kt = 0; kt <= qt; ++kt) {
        const int k0 = kt * 64;
        const ushortT* kg = Kb + ((size_t)bh * T_SEQ + k0 + srow) * HDIM + sk;
        const ushortT* vg = Vt + ((size_t)bh * HDIM + srow) * T_SEQ + k0 + sk;
        __builtin_amdgcn_global_load_lds(GP(kg),             LP(Ks + srow * 64 + sk),        16, 0, 0);
        __builtin_amdgcn_global_load_lds(GP(kg + 32 * HDIM), LP(Ks + (32 + srow) * 64 + sk), 16, 0, 0);
        __builtin_amdgcn_global_load_lds(GP(vg),             LP(Vs + srow * 64 + sk),        16, 0, 0);
        __builtin_amdgcn_global_load_lds(GP(vg + 32 * T_SEQ),LP(Vs + (32 + srow) * 64 + sk), 16, 0, 0);
        __syncthreads();

        // S = Q K^T  (C: col=kv=lane&15 (+16*ni), row=q=lh*4+e)
        f32x4 s[4];
        #pragma unroll
        for (int ni = 0; ni < 4; ++ni) {
            s16x8 b0 = *(const s16x8*)&Ks[(ni * 16 + lr) * 64 + lh * 8];
            s16x8 b1 = *(const s16x8*)&Ks[(ni * 16 + lr) * 64 + 32 + lh * 8];
            f32x4 t = {};
            t = __builtin_amdgcn_mfma_f32_16x16x32_bf16(qf0, b0, t, 0, 0, 0);
            t = __builtin_amdgcn_mfma_f32_16x16x32_bf16(qf1, b1, t, 0, 0, 0);
            s[ni] = t;
        }
        if (kt == qt) {   // diagonal tile: mask kv > q
            #pragma unroll
            for (int ni = 0; ni < 4; ++ni)
                #pragma unroll
                for (int e = 0; e < 4; ++e)
                    if (ni * 16 + lr > w * 16 + lh * 4 + e) s[ni][e] = -1e30f;
        }

        // online softmax (rows j=0..3 live in all 16 lanes of the lh-group)
        #pragma unroll
        for (int e = 0; e < 4; ++e) {
            float pm = fmaxf(fmaxf(s[0][e], s[1][e]), fmaxf(s[2][e], s[3][e]));
            #pragma unroll
            for (int msk = 1; msk < 16; msk <<= 1)
                pm = fmaxf(pm, __shfl_xor(pm, msk, 64));
            const float mn = fmaxf(m_s[e], pm);
            const float sc = __expf(m_s[e] - mn);
            float rs = 0.f;
            #pragma unroll
            for (int ni = 0; ni < 4; ++ni) {
                float p = __expf(s[ni][e] - mn);
                s[ni][e] = p;
                rs += p;
            }
            #pragma unroll
            for (int msk = 1; msk < 16; msk <<= 1)
                rs += __shfl_xor(rs, msk, 64);
            l_s[e] = l_s[e] * sc + rs;
            m_s[e] = mn;
            #pragma unroll
            for (int ni = 0; ni < 4; ++ni) o[ni][e] *= sc;
        }

        // P (C-layout) -> LDS -> A-frags
        #pragma unroll
        for (int ni = 0; ni < 4; ++ni)
            #pragma unroll
            for (int e = 0; e < 4; ++e)
                Ps[w][(lh * 4 + e) * 64 + ni * 16 + lr] = f2b(s[ni][e]);
        __asm__ volatile("s_waitcnt lgkmcnt(0)" ::: "memory");
        const s16x8 pf0 = *(const s16x8*)&Ps[w][lr * 64 + lh * 8];
        const s16x8 pf1 = *(const s16x8*)&Ps[w][lr * 64 + 32 + lh * 8];

        // O += P * V   (B operand from transposed V tile: Vs[d][kv])
        #pragma unroll
        for (int ni = 0; ni < 4; ++ni) {
            s16x8 v0 = *(const s16x8*)&Vs[(ni * 16 + lr) * 64 + lh * 8];
            s16x8 v1 = *(const s16x8*)&Vs[(ni * 16 + lr) * 64 + 32 + lh * 8];
            o[ni] = __builtin_amdgcn_mfma_f32_16x16x32_bf16(pf0, v0, o[ni], 0, 0, 0);
            o[ni] = __builtin_amdgcn_mfma_f32_16x16x32_bf16(pf1, v1, o[ni], 0, 0, 0);
        }
        __syncthreads();
    }

    // epilogue: O / l -> Ob (B,T,D) bf16
    const int b = bh >> 4, h = bh & 15;
    #pragma unroll
    for (int e = 0; e < 4; ++e) {
        const float inv = 1.f / l_s[e];
        const int t = q0 + w * 16 + lh * 4 + e;
        const size_t base = ((size_t)(b * T_SEQ) + t) * D_MODEL + h * HDIM;
        #pragma unroll
        for (int ni = 0; ni < 4; ++ni)
            Ob[base + ni * 16 + lr] = f2b(o[ni][e] * inv);
    }
}

extern "C" void kernel_launch(void* const* d_in, const int* in_sizes, int n_in,
                              void* d_out, int out_size, void* d_ws, size_t ws_size,
                              hipStream_t stream) {
    const float* x  = (const float*)d_in[0];
    const float* Wq = (const float*)d_in[1];
    const float* bq = (const float*)d_in[2];
    const float* Wk = (const float*)d_in[3];
    const float* bk = (const float*)d_in[4];
    const float* Wv = (const float*)d_in[5];
    const float* bv = (const float*)d_in[6];
    const float* Wo = (const float*)d_in[7];
    const float* bo = (const float*)d_in[8];

    ushortT* xb  = (ushortT*)d_ws;                    // 8192*1024
    ushortT* Wqb = xb  + (size_t)M_ROWS * D_MODEL;
    ushortT* Wkb = Wqb + (size_t)D_MODEL * D_MODEL;
    ushortT* Wvb = Wkb + (size_t)D_MODEL * D_MODEL;
    ushortT* Wob = Wvb + (size_t)D_MODEL * D_MODEL;
    ushortT* Qb  = Wob + (size_t)D_MODEL * D_MODEL;   // (BH,T,64)
    ushortT* Kb  = Qb  + (size_t)M_ROWS * D_MODEL;    // (BH,T,64)
    ushortT* Vtb = Kb  + (size_t)M_ROWS * D_MODEL;    // (BH,64,T)
    ushortT* Ob  = Vtb + (size_t)M_ROWS * D_MODEL;    // (B,T,D)

    cast_f32_bf16<<<4096, 256, 0, stream>>>(x,  xb,  M_ROWS * D_MODEL / 8);
    cast_f32_bf16<<<512,  256, 0, stream>>>(Wq, Wqb, D_MODEL * D_MODEL / 8);
    cast_f32_bf16<<<512,  256, 0, stream>>>(Wk, Wkb, D_MODEL * D_MODEL / 8);
    cast_f32_bf16<<<512,  256, 0, stream>>>(Wv, Wvb, D_MODEL * D_MODEL / 8);
    cast_f32_bf16<<<512,  256, 0, stream>>>(Wo, Wob, D_MODEL * D_MODEL / 8);

    dim3 gg(M_ROWS / 128, D_MODEL / 128);
    gemm_bt<<<gg, 256, 0, stream>>>(xb, Wqb, bq, Qb,  0.125f, 0);
    gemm_bt<<<gg, 256, 0, stream>>>(xb, Wkb, bk, Kb,  1.0f,   1);
    gemm_bt<<<gg, 256, 0, stream>>>(xb, Wvb, bv, Vtb, 1.0f,   2);

    attn_fwd<<<dim3(T_SEQ / 64, BATCH * NHEADS), 256, 0, stream>>>(Qb, Kb, Vtb, Ob);

    gemm_bt<<<gg, 256, 0, stream>>>(Ob, Wob, bo, d_out, 1.0f, 3);
}

// Round 3
// 351.780 us; speedup vs baseline: 1.4162x; 1.4162x over previous
//
#include <hip/hip_runtime.h>
#include <hip/hip_bf16.h>

#define D_MODEL 1024
#define T_SEQ   2048
#define BATCH   4
#define NHEADS  16
#define HDIM    64
#define M_ROWS  (BATCH * T_SEQ)   // 8192

typedef unsigned short ushortT;
typedef __attribute__((ext_vector_type(4))) float f32x4;
typedef __attribute__((ext_vector_type(8))) short s16x8;

#define GP(p) ((const __attribute__((address_space(1))) void*)(p))
#define LP(p) ((__attribute__((address_space(3))) void*)(p))

static __device__ __forceinline__ ushortT f2b(float f) {
    union { float f; unsigned u; } v; v.f = f;
    unsigned r = v.u + 0x7fffu + ((v.u >> 16) & 1u);
    return (ushortT)(r >> 16);
}

// ---- cast fp32 -> bf16, 8 elems/thread, stores XOR-swizzled by (row&7) ----
// granule index i (8 elems); row = i>>7 (1024 elems/row); dst granule = i ^ ((i>>7)&7)
__global__ void cast_f32_bf16_swz(const float* __restrict__ src, ushortT* __restrict__ dst, int n8) {
    int i = blockIdx.x * 256 + threadIdx.x;
    if (i >= n8) return;
    const float4* s = (const float4*)src;
    float4 a = s[i * 2], b = s[i * 2 + 1];
    s16x8 r;
    r[0] = f2b(a.x); r[1] = f2b(a.y); r[2] = f2b(a.z); r[3] = f2b(a.w);
    r[4] = f2b(b.x); r[5] = f2b(b.y); r[6] = f2b(b.z); r[7] = f2b(b.w);
    ((s16x8*)dst)[i ^ ((i >> 7) & 7)] = r;
}

// ---------------- GEMM: C[M,N] = A[M,K] * W[N,K]^T + bias ----------------
// A and Bw are stored granule-swizzled: elem[m][k ^ ((m&7)<<3)].
// modes: 0 = Q -> (BH,T,64) bf16 plain (scale folded), 1 = K -> (BH,T,64) bf16 swizzled,
//        2 = V -> (BH,64,T) bf16 transposed+swizzled, 3 = fp32 row-major to d_out.
__global__ __launch_bounds__(256, 2) void gemm_bt(
    const ushortT* __restrict__ A,
    const ushortT* __restrict__ Bw,
    const float*   __restrict__ bias,
    void*          __restrict__ outp,
    float scale, int mode)
{
    __shared__ __attribute__((aligned(16))) ushortT As[128 * 64];
    __shared__ __attribute__((aligned(16))) ushortT Bs[128 * 64];

    const int tid  = threadIdx.x;
    const int wave = tid >> 6, lane = tid & 63;
    const int wm = wave >> 1, wn = wave & 1;
    const int lr = lane & 15, lh = lane >> 4;
    const int m0 = blockIdx.x * 128, n0 = blockIdx.y * 128;

    const int srow = tid >> 3;        // 0..31
    const int sg   = tid & 7;         // granule 0..7

    f32x4 acc[4][4] = {};

    for (int k0 = 0; k0 < 1024; k0 += 64) {
        #pragma unroll
        for (int is = 0; is < 4; ++is) {
            __builtin_amdgcn_global_load_lds(GP(A  + (size_t)(m0 + is * 32 + srow) * 1024 + k0 + sg * 8),
                                             LP(As + is * 2048 + tid * 8), 16, 0, 0);
            __builtin_amdgcn_global_load_lds(GP(Bw + (size_t)(n0 + is * 32 + srow) * 1024 + k0 + sg * 8),
                                             LP(Bs + is * 2048 + tid * 8), 16, 0, 0);
        }
        __syncthreads();

        #pragma unroll
        for (int kk = 0; kk < 2; ++kk) {
            s16x8 af[4], bfr[4];
            const int g = ((kk * 4 + lh) ^ (lr & 7)) * 8;
            #pragma unroll
            for (int i = 0; i < 4; ++i)
                af[i] = *(const s16x8*)&As[(wm * 64 + i * 16 + lr) * 64 + g];
            #pragma unroll
            for (int j = 0; j < 4; ++j)
                bfr[j] = *(const s16x8*)&Bs[(wn * 64 + j * 16 + lr) * 64 + g];
            __builtin_amdgcn_s_setprio(1);
            #pragma unroll
            for (int i = 0; i < 4; ++i)
                #pragma unroll
                for (int j = 0; j < 4; ++j)
                    acc[i][j] = __builtin_amdgcn_mfma_f32_16x16x32_bf16(af[i], bfr[j], acc[i][j], 0, 0, 0);
            __builtin_amdgcn_s_setprio(0);
        }
        __syncthreads();
    }

    #pragma unroll
    for (int i = 0; i < 4; ++i) {
        #pragma unroll
        for (int j = 0; j < 4; ++j) {
            const int c = n0 + wn * 64 + j * 16 + lr;
            const float bv = bias[c];
            #pragma unroll
            for (int e = 0; e < 4; ++e) {
                const int r = m0 + wm * 64 + i * 16 + lh * 4 + e;
                const float val = (acc[i][j][e] + bv) * scale;
                if (mode == 3) {
                    ((float*)outp)[(size_t)r * 1024 + c] = val;
                } else {
                    const int b = r >> 11, t = r & 2047;
                    const int h = c >> 6,  d = c & 63;
                    size_t idx;
                    if (mode == 2)      idx = ((size_t)(b * NHEADS + h) * HDIM + d) * T_SEQ + (t ^ ((d & 7) << 3));
                    else if (mode == 1) idx = ((size_t)(b * NHEADS + h) * T_SEQ + t) * HDIM + (d ^ ((t & 7) << 3));
                    else                idx = ((size_t)(b * NHEADS + h) * T_SEQ + t) * HDIM + d;
                    ((ushortT*)outp)[idx] = f2b(val);
                }
            }
        }
    }
}

// ---------------- flash attention, causal ----------------
// 1D grid of 2048: xcd-grouped by bh (8 heads / XCD -> L2-resident K/V), LPT qt order.
// Q: (BH,T,64) plain. K: (BH,T,64) swizzled d^=(t&7)<<3. Vt: (BH,64,T) swizzled t^=(d&7)<<3.
// Ob out: (B,T,D) bf16, swizzled c^=(t&7)<<3 (consumed by mode-3 GEMM).
__global__ __launch_bounds__(256, 4) void attn_fwd(
    const ushortT* __restrict__ Qb, const ushortT* __restrict__ Kb,
    const ushortT* __restrict__ Vt, ushortT* __restrict__ Ob)
{
    __shared__ __attribute__((aligned(16))) ushortT Ks[2][64 * 64];
    __shared__ __attribute__((aligned(16))) ushortT Vs[2][64 * 64];
    __shared__ __attribute__((aligned(16))) ushortT Ps[4][16 * 64];

    const int tid = threadIdx.x;
    const int w = tid >> 6, lane = tid & 63;
    const int lr = lane & 15, lh = lane >> 4;

    const int blk = blockIdx.x;
    const int j   = blk >> 3;
    const int bh  = (blk & 7) * 8 + (j >> 5);
    const int qt  = 31 - (j & 31);
    const int q0  = qt * 64;

    // Q fragments (A operand): row = q0 + w*16 + lr
    const ushortT* qrow = Qb + ((size_t)bh * T_SEQ + q0 + w * 16 + lr) * HDIM;
    const s16x8 qf0 = *(const s16x8*)(qrow + lh * 8);
    const s16x8 qf1 = *(const s16x8*)(qrow + 32 + lh * 8);

    float m_s[4], l_s[4];
    f32x4 o[4] = {};
    #pragma unroll
    for (int e = 0; e < 4; ++e) { m_s[e] = -1e30f; l_s[e] = 0.f; }

    const int srow = tid >> 3;       // 0..31
    const int sk   = (tid & 7) * 8;  // 0..56

    const ushortT* Kbh = Kb + (size_t)bh * T_SEQ * HDIM;
    const ushortT* Vbh = Vt + (size_t)bh * HDIM * T_SEQ;

    #define STAGE(buf, kt_) do { \
        const int k0_ = (kt_) * 64; \
        const ushortT* kg = Kbh + (size_t)(k0_ + srow) * HDIM + sk; \
        const ushortT* vg = Vbh + (size_t)srow * T_SEQ + k0_ + sk; \
        __builtin_amdgcn_global_load_lds(GP(kg),                 LP(&Ks[buf][srow * 64 + sk]),        16, 0, 0); \
        __builtin_amdgcn_global_load_lds(GP(kg + 32 * HDIM),     LP(&Ks[buf][(32 + srow) * 64 + sk]), 16, 0, 0); \
        __builtin_amdgcn_global_load_lds(GP(vg),                 LP(&Vs[buf][srow * 64 + sk]),        16, 0, 0); \
        __builtin_amdgcn_global_load_lds(GP(vg + 32 * T_SEQ),    LP(&Vs[buf][(32 + srow) * 64 + sk]), 16, 0, 0); \
    } while (0)

    STAGE(0, 0);
    __syncthreads();

    const int g0 = (lh       ^ (lr & 7)) * 8;   // swizzled granule, k-half 0
    const int g1 = ((4 + lh) ^ (lr & 7)) * 8;   // swizzled granule, k-half 1

    for (int kt = 0; kt <= qt; ++kt) {
        const int cur = kt & 1;
        if (kt < qt) STAGE(cur ^ 1, kt + 1);

        // S = Q K^T  (C: col=kv=ni*16+lr, row=q=lh*4+e)
        f32x4 s[4];
        __builtin_amdgcn_s_setprio(1);
        #pragma unroll
        for (int ni = 0; ni < 4; ++ni) {
            const int rr = ni * 16 + lr;
            s16x8 b0 = *(const s16x8*)&Ks[cur][rr * 64 + g0];
            s16x8 b1 = *(const s16x8*)&Ks[cur][rr * 64 + g1];
            f32x4 t = {};
            t = __builtin_amdgcn_mfma_f32_16x16x32_bf16(qf0, b0, t, 0, 0, 0);
            t = __builtin_amdgcn_mfma_f32_16x16x32_bf16(qf1, b1, t, 0, 0, 0);
            s[ni] = t;
        }
        __builtin_amdgcn_s_setprio(0);

        if (kt == qt) {   // diagonal tile: mask kv > q
            #pragma unroll
            for (int ni = 0; ni < 4; ++ni)
                #pragma unroll
                for (int e = 0; e < 4; ++e)
                    if (ni * 16 + lr > w * 16 + lh * 4 + e) s[ni][e] = -1e30f;
        }

        // online softmax over the 16-lane row group
        #pragma unroll
        for (int e = 0; e < 4; ++e) {
            float pm = fmaxf(fmaxf(s[0][e], s[1][e]), fmaxf(s[2][e], s[3][e]));
            #pragma unroll
            for (int msk = 1; msk < 16; msk <<= 1)
                pm = fmaxf(pm, __shfl_xor(pm, msk, 64));
            const float mn = fmaxf(m_s[e], pm);
            const float sc = __expf(m_s[e] - mn);
            float rs = 0.f;
            #pragma unroll
            for (int ni = 0; ni < 4; ++ni) {
                float p = __expf(s[ni][e] - mn);
                s[ni][e] = p;
                rs += p;
            }
            #pragma unroll
            for (int msk = 1; msk < 16; msk <<= 1)
                rs += __shfl_xor(rs, msk, 64);
            l_s[e] = l_s[e] * sc + rs;
            m_s[e] = mn;
            #pragma unroll
            for (int ni = 0; ni < 4; ++ni) o[ni][e] *= sc;
        }

        // P (C-layout) -> LDS (swizzled by row&7) -> A-frags
        #pragma unroll
        for (int ni = 0; ni < 4; ++ni)
            #pragma unroll
            for (int e = 0; e < 4; ++e) {
                const int r = lh * 4 + e;
                Ps[w][r * 64 + ((ni * 16 + lr) ^ ((r & 7) << 3))] = f2b(s[ni][e]);
            }
        __asm__ volatile("s_waitcnt lgkmcnt(0)" ::: "memory");
        __builtin_amdgcn_sched_barrier(0);
        const s16x8 pf0 = *(const s16x8*)&Ps[w][lr * 64 + g0];
        const s16x8 pf1 = *(const s16x8*)&Ps[w][lr * 64 + g1];

        // O += P * V   (B operand from transposed V tile: Vs[d][kv])
        __builtin_amdgcn_s_setprio(1);
        #pragma unroll
        for (int ni = 0; ni < 4; ++ni) {
            const int dd = ni * 16 + lr;
            s16x8 v0 = *(const s16x8*)&Vs[cur][dd * 64 + g0];
            s16x8 v1 = *(const s16x8*)&Vs[cur][dd * 64 + g1];
            o[ni] = __builtin_amdgcn_mfma_f32_16x16x32_bf16(pf0, v0, o[ni], 0, 0, 0);
            o[ni] = __builtin_amdgcn_mfma_f32_16x16x32_bf16(pf1, v1, o[ni], 0, 0, 0);
        }
        __builtin_amdgcn_s_setprio(0);
        __syncthreads();
    }

    // epilogue: O / l -> Ob (B,T,D) bf16, column-swizzled by (t&7) for the mode-3 GEMM
    const int b = bh >> 4, h = bh & 15;
    #pragma unroll
    for (int e = 0; e < 4; ++e) {
        const float inv = 1.f / l_s[e];
        const int t = q0 + w * 16 + lh * 4 + e;
        const size_t base = ((size_t)(b * T_SEQ) + t) * D_MODEL;
        #pragma unroll
        for (int ni = 0; ni < 4; ++ni) {
            const int c = h * HDIM + ni * 16 + lr;
            Ob[base + (c ^ ((t & 7) << 3))] = f2b(o[ni][e] * inv);
        }
    }
}

extern "C" void kernel_launch(void* const* d_in, const int* in_sizes, int n_in,
                              void* d_out, int out_size, void* d_ws, size_t ws_size,
                              hipStream_t stream) {
    const float* x  = (const float*)d_in[0];
    const float* Wq = (const float*)d_in[1];
    const float* bq = (const float*)d_in[2];
    const float* Wk = (const float*)d_in[3];
    const float* bk = (const float*)d_in[4];
    const float* Wv = (const float*)d_in[5];
    const float* bv = (const float*)d_in[6];
    const float* Wo = (const float*)d_in[7];
    const float* bo = (const float*)d_in[8];

    ushortT* xb  = (ushortT*)d_ws;                    // 8192*1024, swizzled
    ushortT* Wqb = xb  + (size_t)M_ROWS * D_MODEL;    // swizzled
    ushortT* Wkb = Wqb + (size_t)D_MODEL * D_MODEL;
    ushortT* Wvb = Wkb + (size_t)D_MODEL * D_MODEL;
    ushortT* Wob = Wvb + (size_t)D_MODEL * D_MODEL;
    ushortT* Qb  = Wob + (size_t)D_MODEL * D_MODEL;   // (BH,T,64) plain
    ushortT* Kb  = Qb  + (size_t)M_ROWS * D_MODEL;    // (BH,T,64) swizzled
    ushortT* Vtb = Kb  + (size_t)M_ROWS * D_MODEL;    // (BH,64,T) swizzled
    ushortT* Ob  = Vtb + (size_t)M_ROWS * D_MODEL;    // (B,T,D)  swizzled

    cast_f32_bf16_swz<<<4096, 256, 0, stream>>>(x,  xb,  M_ROWS * D_MODEL / 8);
    cast_f32_bf16_swz<<<512,  256, 0, stream>>>(Wq, Wqb, D_MODEL * D_MODEL / 8);
    cast_f32_bf16_swz<<<512,  256, 0, stream>>>(Wk, Wkb, D_MODEL * D_MODEL / 8);
    cast_f32_bf16_swz<<<512,  256, 0, stream>>>(Wv, Wvb, D_MODEL * D_MODEL / 8);
    cast_f32_bf16_swz<<<512,  256, 0, stream>>>(Wo, Wob, D_MODEL * D_MODEL / 8);

    dim3 gg(M_ROWS / 128, D_MODEL / 128);
    gemm_bt<<<gg, 256, 0, stream>>>(xb, Wqb, bq, Qb,  0.125f, 0);
    gemm_bt<<<gg, 256, 0, stream>>>(xb, Wkb, bk, Kb,  1.0f,   1);
    gemm_bt<<<gg, 256, 0, stream>>>(xb, Wvb, bv, Vtb, 1.0f,   2);

    attn_fwd<<<2048, 256, 0, stream>>>(Qb, Kb, Vtb, Ob);

    gemm_bt<<<gg, 256, 0, stream>>>(Ob, Wob, bo, d_out, 1.0f, 3);
}

// Round 5
// 309.451 us; speedup vs baseline: 1.6099x; 1.1368x over previous
//
#include <hip/hip_runtime.h>
#include <hip/hip_bf16.h>

#define D_MODEL 1024
#define T_SEQ   2048
#define BATCH   4
#define NHEADS  16
#define HDIM    64
#define M_ROWS  (BATCH * T_SEQ)   // 8192
#define QSCALE  (0.125f * 1.44269504088896340736f)   // 1/sqrt(64) * log2(e)

typedef unsigned short ushortT;
typedef __attribute__((ext_vector_type(4))) float f32x4;
typedef __attribute__((ext_vector_type(8))) short s16x8;

#define GP(p) ((const __attribute__((address_space(1))) void*)(p))
#define LP(p) ((__attribute__((address_space(3))) void*)(p))

static __device__ __forceinline__ ushortT f2b(float f) {
    union { float f; unsigned u; } v; v.f = f;
    unsigned r = v.u + 0x7fffu + ((v.u >> 16) & 1u);
    return (ushortT)(r >> 16);
}

// ---- cast fp32 -> bf16, 8 elems/thread, stores XOR-swizzled by (row&7) ----
__global__ void cast_f32_bf16_swz(const float* __restrict__ src, ushortT* __restrict__ dst, int n8) {
    int i = blockIdx.x * 256 + threadIdx.x;
    if (i >= n8) return;
    const float4* s = (const float4*)src;
    float4 a = s[i * 2], b = s[i * 2 + 1];
    s16x8 r;
    r[0] = f2b(a.x); r[1] = f2b(a.y); r[2] = f2b(a.z); r[3] = f2b(a.w);
    r[4] = f2b(b.x); r[5] = f2b(b.y); r[6] = f2b(b.z); r[7] = f2b(b.w);
    ((s16x8*)dst)[i ^ ((i >> 7) & 7)] = r;
}

// ================= shared GEMM machinery (2-phase, double-buffered) =================
// A and Bw stored granule-swizzled: elem[m][k ^ ((m&7)<<3)].
// 128x128 tile, BK=64, 4 waves (2x2), 16 K-steps.

#define GEMM_PREAMBLE()                                                  \
    const int tid  = threadIdx.x;                                        \
    const int wave = tid >> 6, lane = tid & 63;                          \
    const int wm = wave >> 1, wn = wave & 1;                             \
    const int lr = lane & 15, lh = lane >> 4;                            \
    const int srow = tid >> 3;                                           \
    const int sg   = tid & 7;                                            \
    f32x4 acc[4][4] = {};                                                \
    const ushortT* Ag = A  + (size_t)(m0 + srow) * 1024 + sg * 8;        \
    const ushortT* Bg = Bw + (size_t)(n0 + srow) * 1024 + sg * 8;

#define STAGE_G(buf, k0)                                                               \
    do {                                                                               \
        _Pragma("unroll")                                                              \
        for (int is = 0; is < 4; ++is) {                                               \
            __builtin_amdgcn_global_load_lds(GP(Ag + (size_t)(is * 32) * 1024 + (k0)), \
                                             LP(&As[buf][is * 2048 + tid * 8]), 16, 0, 0); \
            __builtin_amdgcn_global_load_lds(GP(Bg + (size_t)(is * 32) * 1024 + (k0)), \
                                             LP(&Bs[buf][is * 2048 + tid * 8]), 16, 0, 0); \
        }                                                                              \
    } while (0)

#define COMPUTE_G(buf)                                                                 \
    do {                                                                               \
        _Pragma("unroll")                                                              \
        for (int kk = 0; kk < 2; ++kk) {                                               \
            s16x8 af[4], bfr[4];                                                       \
            const int g = ((kk * 4 + lh) ^ (lr & 7)) * 8;                              \
            _Pragma("unroll")                                                          \
            for (int i = 0; i < 4; ++i)                                                \
                af[i] = *(const s16x8*)&As[buf][(wm * 64 + i * 16 + lr) * 64 + g];     \
            _Pragma("unroll")                                                          \
            for (int j = 0; j < 4; ++j)                                                \
                bfr[j] = *(const s16x8*)&Bs[buf][(wn * 64 + j * 16 + lr) * 64 + g];    \
            __builtin_amdgcn_s_setprio(1);                                             \
            _Pragma("unroll")                                                          \
            for (int i = 0; i < 4; ++i)                                                \
                _Pragma("unroll")                                                      \
                for (int j = 0; j < 4; ++j)                                            \
                    acc[i][j] = __builtin_amdgcn_mfma_f32_16x16x32_bf16(af[i], bfr[j], acc[i][j], 0, 0, 0); \
            __builtin_amdgcn_s_setprio(0);                                             \
        }                                                                              \
    } while (0)

#define GEMM_KLOOP()                        \
    STAGE_G(0, 0);                          \
    __syncthreads();                        \
    for (int t = 0; t < 15; ++t) {          \
        const int cur = t & 1;              \
        STAGE_G(cur ^ 1, (t + 1) * 64);     \
        COMPUTE_G(cur);                     \
        __syncthreads();                    \
    }                                       \
    COMPUTE_G(1);

// ---- fused QKV GEMM: grid (64, 24); seg = y>>3 (0=Q,1=K,2=V) ----
__global__ __launch_bounds__(256, 2) void qkv_gemm(
    const ushortT* __restrict__ A,
    const ushortT* __restrict__ Wq, const ushortT* __restrict__ Wk, const ushortT* __restrict__ Wv,
    const float* __restrict__ bq, const float* __restrict__ bk, const float* __restrict__ bv,
    ushortT* __restrict__ Qb, ushortT* __restrict__ Kb, ushortT* __restrict__ Vtb)
{
    __shared__ __attribute__((aligned(16))) ushortT As[2][128 * 64];
    __shared__ __attribute__((aligned(16))) ushortT Bs[2][128 * 64];

    const int seg = blockIdx.y >> 3;
    const int m0 = blockIdx.x * 128, n0 = (blockIdx.y & 7) * 128;
    const ushortT* Bw   = (seg == 0) ? Wq : (seg == 1) ? Wk : Wv;
    const float*   bias = (seg == 0) ? bq : (seg == 1) ? bk : bv;
    const float    scale = (seg == 0) ? QSCALE : 1.0f;

    GEMM_PREAMBLE();
    GEMM_KLOOP();

    ushortT* outp = (seg == 0) ? Qb : (seg == 1) ? Kb : Vtb;
    #pragma unroll
    for (int i = 0; i < 4; ++i) {
        #pragma unroll
        for (int j = 0; j < 4; ++j) {
            const int c = n0 + wn * 64 + j * 16 + lr;
            const float bv_ = bias[c];
            #pragma unroll
            for (int e = 0; e < 4; ++e) {
                const int r = m0 + wm * 64 + i * 16 + lh * 4 + e;
                const float val = (acc[i][j][e] + bv_) * scale;
                const int b = r >> 11, t = r & 2047;
                const int h = c >> 6,  d = c & 63;
                size_t idx;
                if (seg == 2)      idx = ((size_t)(b * NHEADS + h) * HDIM + d) * T_SEQ + (t ^ ((d & 7) << 3));
                else if (seg == 1) idx = ((size_t)(b * NHEADS + h) * T_SEQ + t) * HDIM + (d ^ ((t & 7) << 3));
                else               idx = ((size_t)(b * NHEADS + h) * T_SEQ + t) * HDIM + d;
                outp[idx] = f2b(val);
            }
        }
    }
}

// ---- output GEMM: grid (64, 8), fp32 out ----
__global__ __launch_bounds__(256, 2) void out_gemm(
    const ushortT* __restrict__ A, const ushortT* __restrict__ Bw,
    const float* __restrict__ bias, float* __restrict__ outp)
{
    __shared__ __attribute__((aligned(16))) ushortT As[2][128 * 64];
    __shared__ __attribute__((aligned(16))) ushortT Bs[2][128 * 64];

    const int m0 = blockIdx.x * 128, n0 = blockIdx.y * 128;

    GEMM_PREAMBLE();
    GEMM_KLOOP();

    #pragma unroll
    for (int i = 0; i < 4; ++i) {
        #pragma unroll
        for (int j = 0; j < 4; ++j) {
            const int c = n0 + wn * 64 + j * 16 + lr;
            const float bv_ = bias[c];
            #pragma unroll
            for (int e = 0; e < 4; ++e) {
                const int r = m0 + wm * 64 + i * 16 + lh * 4 + e;
                outp[(size_t)r * 1024 + c] = acc[i][j][e] + bv_;
            }
        }
    }
}

// ---------------- flash attention, causal, swapped-operand softmax ----------------
// Q pre-scaled by QSCALE (log2 domain). K: (BH,T,64) swizzled d^=(t&7)<<3.
// Vt: (BH,64,T) swizzled t^=(d&7)<<3.  Ob out: (B,T,D) bf16 swizzled c^=(t&7)<<3.
__global__ __launch_bounds__(256, 4) void attn_fwd(
    const ushortT* __restrict__ Qb, const ushortT* __restrict__ Kb,
    const ushortT* __restrict__ Vt, ushortT* __restrict__ Ob)
{
    __shared__ __attribute__((aligned(16))) ushortT Ks[2][64 * 64];
    __shared__ __attribute__((aligned(16))) ushortT Vs[2][64 * 64];
    __shared__ __attribute__((aligned(16))) ushortT Ps[4][16 * 64];

    const int tid = threadIdx.x;
    const int w = tid >> 6, lane = tid & 63;
    const int lr = lane & 15, lh = lane >> 4;

    const int blk = blockIdx.x;
    const int j   = blk >> 3;
    const int bh  = (blk & 7) * 8 + (j >> 5);
    const int qt  = 31 - (j & 31);
    const int q0  = qt * 64;

    // Q fragments: serve as B-operand (col=q=lane&15) for swapped QK^T
    const ushortT* qrow = Qb + ((size_t)bh * T_SEQ + q0 + w * 16 + lr) * HDIM;
    const s16x8 qf0 = *(const s16x8*)(qrow + lh * 8);
    const s16x8 qf1 = *(const s16x8*)(qrow + 32 + lh * 8);

    float m_r = -1e30f, l_r = 0.f;
    f32x4 o[4] = {};   // O^T: col=q=lr, row=d=ni*16+lh*4+e

    const int srow = tid >> 3;
    const int sk   = (tid & 7) * 8;

    const ushortT* Kbh = Kb + (size_t)bh * T_SEQ * HDIM;
    const ushortT* Vbh = Vt + (size_t)bh * HDIM * T_SEQ;

    #define STAGE(buf, kt_) do { \
        const int k0_ = (kt_) * 64; \
        const ushortT* kg = Kbh + (size_t)(k0_ + srow) * HDIM + sk; \
        const ushortT* vg = Vbh + (size_t)srow * T_SEQ + k0_ + sk; \
        __builtin_amdgcn_global_load_lds(GP(kg),                 LP(&Ks[buf][srow * 64 + sk]),        16, 0, 0); \
        __builtin_amdgcn_global_load_lds(GP(kg + 32 * HDIM),     LP(&Ks[buf][(32 + srow) * 64 + sk]), 16, 0, 0); \
        __builtin_amdgcn_global_load_lds(GP(vg),                 LP(&Vs[buf][srow * 64 + sk]),        16, 0, 0); \
        __builtin_amdgcn_global_load_lds(GP(vg + 32 * T_SEQ),    LP(&Vs[buf][(32 + srow) * 64 + sk]), 16, 0, 0); \
    } while (0)

    STAGE(0, 0);
    __syncthreads();

    const int g0 = (lh       ^ (lr & 7)) * 8;
    const int g1 = ((4 + lh) ^ (lr & 7)) * 8;

    for (int kt = 0; kt <= qt; ++kt) {
        const int cur = kt & 1;
        if (kt < qt) STAGE(cur ^ 1, kt + 1);

        // S^T = K Q^T: A=K-frag, B=Q-frag.  s[ni][e] = S[q=w*16+lr][kv=ni*16+lh*4+e]
        f32x4 s[4];
        __builtin_amdgcn_s_setprio(1);
        #pragma unroll
        for (int ni = 0; ni < 4; ++ni) {
            const int rr = ni * 16 + lr;
            s16x8 b0 = *(const s16x8*)&Ks[cur][rr * 64 + g0];
            s16x8 b1 = *(const s16x8*)&Ks[cur][rr * 64 + g1];
            f32x4 t = {};
            t = __builtin_amdgcn_mfma_f32_16x16x32_bf16(b0, qf0, t, 0, 0, 0);
            t = __builtin_amdgcn_mfma_f32_16x16x32_bf16(b1, qf1, t, 0, 0, 0);
            s[ni] = t;
        }
        __builtin_amdgcn_s_setprio(0);

        if (kt == qt) {   // diagonal tile: mask kv > q
            #pragma unroll
            for (int ni = 0; ni < 4; ++ni)
                #pragma unroll
                for (int e = 0; e < 4; ++e)
                    if (ni * 16 + lh * 4 + e > w * 16 + lr) s[ni][e] = -1e30f;
        }

        // per-lane online softmax for q-row lr (16 values here + 2 shfl to combine lh groups)
        float pm = -1e30f;
        #pragma unroll
        for (int ni = 0; ni < 4; ++ni)
            #pragma unroll
            for (int e = 0; e < 4; ++e)
                pm = fmaxf(pm, s[ni][e]);
        pm = fmaxf(pm, __shfl_xor(pm, 16, 64));
        pm = fmaxf(pm, __shfl_xor(pm, 32, 64));
        const float mn = fmaxf(m_r, pm);
        const float sc = exp2f(m_r - mn);
        float rs = 0.f;
        #pragma unroll
        for (int ni = 0; ni < 4; ++ni)
            #pragma unroll
            for (int e = 0; e < 4; ++e) {
                const float p = exp2f(s[ni][e] - mn);
                s[ni][e] = p;
                rs += p;
            }
        rs += __shfl_xor(rs, 16, 64);
        rs += __shfl_xor(rs, 32, 64);
        l_r = l_r * sc + rs;
        m_r = mn;
        #pragma unroll
        for (int ni = 0; ni < 4; ++ni) o[ni] *= sc;

        // P -> LDS: lane owns (q=lr, kv=ni*16+lh*4+e); 8B stores, swizzled by (q&7)
        #pragma unroll
        for (int ni = 0; ni < 4; ++ni) {
            const unsigned u0 = (unsigned)f2b(s[ni][0]) | ((unsigned)f2b(s[ni][1]) << 16);
            const unsigned u1 = (unsigned)f2b(s[ni][2]) | ((unsigned)f2b(s[ni][3]) << 16);
            *(uint2*)&Ps[w][lr * 64 + ((ni * 16 + lh * 4) ^ ((lr & 7) << 3))] = make_uint2(u0, u1);
        }
        __asm__ volatile("s_waitcnt lgkmcnt(0)" ::: "memory");
        __builtin_amdgcn_sched_barrier(0);
        const s16x8 pf0 = *(const s16x8*)&Ps[w][lr * 64 + g0];   // P^T B-frag: col=q=lr, k=kv
        const s16x8 pf1 = *(const s16x8*)&Ps[w][lr * 64 + g1];

        // O^T += V^T P^T: A=V^T-frag, B=P^T-frag
        __builtin_amdgcn_s_setprio(1);
        #pragma unroll
        for (int ni = 0; ni < 4; ++ni) {
            const int dd = ni * 16 + lr;
            s16x8 v0 = *(const s16x8*)&Vs[cur][dd * 64 + g0];
            s16x8 v1 = *(const s16x8*)&Vs[cur][dd * 64 + g1];
            o[ni] = __builtin_amdgcn_mfma_f32_16x16x32_bf16(v0, pf0, o[ni], 0, 0, 0);
            o[ni] = __builtin_amdgcn_mfma_f32_16x16x32_bf16(v1, pf1, o[ni], 0, 0, 0);
        }
        __builtin_amdgcn_s_setprio(0);
        __syncthreads();
    }

    // epilogue: lane owns q-row t=q0+w*16+lr, d=ni*16+lh*4+e; 8B stores, col-swizzled
    const int b = bh >> 4, h = bh & 15;
    const int t = q0 + w * 16 + lr;
    const float inv = 1.f / l_r;
    const size_t base = ((size_t)(b * T_SEQ) + t) * D_MODEL;
    #pragma unroll
    for (int ni = 0; ni < 4; ++ni) {
        const unsigned u0 = (unsigned)f2b(o[ni][0] * inv) | ((unsigned)f2b(o[ni][1] * inv) << 16);
        const unsigned u1 = (unsigned)f2b(o[ni][2] * inv) | ((unsigned)f2b(o[ni][3] * inv) << 16);
        const int c = h * HDIM + ni * 16 + lh * 4;
        *(uint2*)&Ob[base + (c ^ ((t & 7) << 3))] = make_uint2(u0, u1);
    }
}

extern "C" void kernel_launch(void* const* d_in, const int* in_sizes, int n_in,
                              void* d_out, int out_size, void* d_ws, size_t ws_size,
                              hipStream_t stream) {
    const float* x  = (const float*)d_in[0];
    const float* Wq = (const float*)d_in[1];
    const float* bq = (const float*)d_in[2];
    const float* Wk = (const float*)d_in[3];
    const float* bk = (const float*)d_in[4];
    const float* Wv = (const float*)d_in[5];
    const float* bv = (const float*)d_in[6];
    const float* Wo = (const float*)d_in[7];
    const float* bo = (const float*)d_in[8];

    ushortT* xb  = (ushortT*)d_ws;                    // swizzled bf16 copies
    ushortT* Wqb = xb  + (size_t)M_ROWS * D_MODEL;
    ushortT* Wkb = Wqb + (size_t)D_MODEL * D_MODEL;
    ushortT* Wvb = Wkb + (size_t)D_MODEL * D_MODEL;
    ushortT* Wob = Wvb + (size_t)D_MODEL * D_MODEL;
    ushortT* Qb  = Wob + (size_t)D_MODEL * D_MODEL;   // (BH,T,64) plain, log2-scaled
    ushortT* Kb  = Qb  + (size_t)M_ROWS * D_MODEL;    // (BH,T,64) swizzled
    ushortT* Vtb = Kb  + (size_t)M_ROWS * D_MODEL;    // (BH,64,T) swizzled
    ushortT* Ob  = Vtb + (size_t)M_ROWS * D_MODEL;    // (B,T,D)  swizzled

    cast_f32_bf16_swz<<<4096, 256, 0, stream>>>(x,  xb,  M_ROWS * D_MODEL / 8);
    cast_f32_bf16_swz<<<512,  256, 0, stream>>>(Wq, Wqb, D_MODEL * D_MODEL / 8);
    cast_f32_bf16_swz<<<512,  256, 0, stream>>>(Wk, Wkb, D_MODEL * D_MODEL / 8);
    cast_f32_bf16_swz<<<512,  256, 0, stream>>>(Wv, Wvb, D_MODEL * D_MODEL / 8);
    cast_f32_bf16_swz<<<512,  256, 0, stream>>>(Wo, Wob, D_MODEL * D_MODEL / 8);

    qkv_gemm<<<dim3(64, 24), 256, 0, stream>>>(xb, Wqb, Wkb, Wvb, bq, bk, bv, Qb, Kb, Vtb);

    attn_fwd<<<2048, 256, 0, stream>>>(Qb, Kb, Vtb, Ob);

    out_gemm<<<dim3(64, 8), 256, 0, stream>>>(Ob, Wob, bo, (float*)d_out);
}

// Round 6
// 296.254 us; speedup vs baseline: 1.6816x; 1.0445x over previous
//
#include <hip/hip_runtime.h>
#include <hip/hip_bf16.h>

#define D_MODEL 1024
#define T_SEQ   2048
#define BATCH   4
#define NHEADS  16
#define HDIM    64
#define M_ROWS  (BATCH * T_SEQ)   // 8192
#define QSCALE  (0.125f * 1.44269504088896340736f)   // 1/sqrt(64) * log2(e)

typedef unsigned short ushortT;
typedef __attribute__((ext_vector_type(4))) float f32x4;
typedef __attribute__((ext_vector_type(8))) short s16x8;

#define GP(p) ((const __attribute__((address_space(1))) void*)(p))
#define LP(p) ((__attribute__((address_space(3))) void*)(p))

static __device__ __forceinline__ ushortT f2b(float f) {
    union { float f; unsigned u; } v; v.f = f;
    unsigned r = v.u + 0x7fffu + ((v.u >> 16) & 1u);
    return (ushortT)(r >> 16);
}

// packed f32x2 -> bf16x2 (hardware cvt, S0->low, S1->high)
static __device__ __forceinline__ unsigned cvtpk(float lo, float hi) {
    unsigned r;
    asm("v_cvt_pk_bf16_f32 %0, %1, %2" : "=v"(r) : "v"(lo), "v"(hi));
    return r;
}

// ---- fused cast: x + 4 weights, fp32 -> bf16, XOR-swizzled by (row&7) ----
// granule = 8 elems; rows are 1024 elems = 128 granules for every tensor.
// dst regions contiguous: xb(1048576 gran) Wq Wk Wv Wo (131072 each).
__global__ void cast_all(const float* __restrict__ x,
                         const float* __restrict__ Wq, const float* __restrict__ Wk,
                         const float* __restrict__ Wv, const float* __restrict__ Wo,
                         ushortT* __restrict__ dst) {
    const int i = blockIdx.x * 256 + threadIdx.x;
    const float* src; int g, ob;
    if (i < 1048576)      { src = x;  g = i;           ob = 0; }
    else if (i < 1179648) { src = Wq; g = i - 1048576; ob = 1048576; }
    else if (i < 1310720) { src = Wk; g = i - 1179648; ob = 1179648; }
    else if (i < 1441792) { src = Wv; g = i - 1310720; ob = 1310720; }
    else                  { src = Wo; g = i - 1441792; ob = 1441792; }
    const float4* s = (const float4*)src;
    float4 a = s[g * 2], b = s[g * 2 + 1];
    s16x8 r;
    r[0] = f2b(a.x); r[1] = f2b(a.y); r[2] = f2b(a.z); r[3] = f2b(a.w);
    r[4] = f2b(b.x); r[5] = f2b(b.y); r[6] = f2b(b.z); r[7] = f2b(b.w);
    ((s16x8*)dst)[ob + (g ^ ((g >> 7) & 7))] = r;
}

// ================= shared GEMM machinery (2-phase, double-buffered) =================
// A and Bw stored granule-swizzled: elem[m][k ^ ((m&7)<<3)].
// 128x128 tile, BK=64, 4 waves (2x2), 16 K-steps.

#define GEMM_PREAMBLE()                                                  \
    const int tid  = threadIdx.x;                                        \
    const int wave = tid >> 6, lane = tid & 63;                          \
    const int wm = wave >> 1, wn = wave & 1;                             \
    const int lr = lane & 15, lh = lane >> 4;                            \
    const int srow = tid >> 3;                                           \
    const int sg   = tid & 7;                                            \
    f32x4 acc[4][4] = {};                                                \
    const ushortT* Ag = A  + (size_t)(m0 + srow) * 1024 + sg * 8;        \
    const ushortT* Bg = Bw + (size_t)(n0 + srow) * 1024 + sg * 8;

#define STAGE_G(buf, k0)                                                               \
    do {                                                                               \
        _Pragma("unroll")                                                              \
        for (int is = 0; is < 4; ++is) {                                               \
            __builtin_amdgcn_global_load_lds(GP(Ag + (size_t)(is * 32) * 1024 + (k0)), \
                                             LP(&As[buf][is * 2048 + tid * 8]), 16, 0, 0); \
            __builtin_amdgcn_global_load_lds(GP(Bg + (size_t)(is * 32) * 1024 + (k0)), \
                                             LP(&Bs[buf][is * 2048 + tid * 8]), 16, 0, 0); \
        }                                                                              \
    } while (0)

#define COMPUTE_G(buf)                                                                 \
    do {                                                                               \
        _Pragma("unroll")                                                              \
        for (int kk = 0; kk < 2; ++kk) {                                               \
            s16x8 af[4], bfr[4];                                                       \
            const int g = ((kk * 4 + lh) ^ (lr & 7)) * 8;                              \
            _Pragma("unroll")                                                          \
            for (int i = 0; i < 4; ++i)                                                \
                af[i] = *(const s16x8*)&As[buf][(wm * 64 + i * 16 + lr) * 64 + g];     \
            _Pragma("unroll")                                                          \
            for (int j = 0; j < 4; ++j)                                                \
                bfr[j] = *(const s16x8*)&Bs[buf][(wn * 64 + j * 16 + lr) * 64 + g];    \
            __builtin_amdgcn_s_setprio(1);                                             \
            _Pragma("unroll")                                                          \
            for (int i = 0; i < 4; ++i)                                                \
                _Pragma("unroll")                                                      \
                for (int j = 0; j < 4; ++j)                                            \
                    acc[i][j] = __builtin_amdgcn_mfma_f32_16x16x32_bf16(af[i], bfr[j], acc[i][j], 0, 0, 0); \
            __builtin_amdgcn_s_setprio(0);                                             \
        }                                                                              \
    } while (0)

#define GEMM_KLOOP()                        \
    STAGE_G(0, 0);                          \
    __syncthreads();                        \
    for (int t = 0; t < 15; ++t) {          \
        const int cur = t & 1;              \
        STAGE_G(cur ^ 1, (t + 1) * 64);     \
        COMPUTE_G(cur);                     \
        __syncthreads();                    \
    }                                       \
    COMPUTE_G(1);

// ---- fused QKV GEMM: grid (64, 24); seg = y>>3 (0=Q,1=K,2=V) ----
__global__ __launch_bounds__(256, 2) void qkv_gemm(
    const ushortT* __restrict__ A,
    const ushortT* __restrict__ Wq, const ushortT* __restrict__ Wk, const ushortT* __restrict__ Wv,
    const float* __restrict__ bq, const float* __restrict__ bk, const float* __restrict__ bv,
    ushortT* __restrict__ Qb, ushortT* __restrict__ Kb, ushortT* __restrict__ Vtb)
{
    __shared__ __attribute__((aligned(16))) ushortT As[2][128 * 64];
    __shared__ __attribute__((aligned(16))) ushortT Bs[2][128 * 64];

    const int seg = blockIdx.y >> 3;
    const int m0 = blockIdx.x * 128, n0 = (blockIdx.y & 7) * 128;
    const ushortT* Bw   = (seg == 0) ? Wq : (seg == 1) ? Wk : Wv;
    const float*   bias = (seg == 0) ? bq : (seg == 1) ? bk : bv;
    const float    scale = (seg == 0) ? QSCALE : 1.0f;

    GEMM_PREAMBLE();
    GEMM_KLOOP();

    ushortT* outp = (seg == 0) ? Qb : (seg == 1) ? Kb : Vtb;
    #pragma unroll
    for (int i = 0; i < 4; ++i) {
        #pragma unroll
        for (int j = 0; j < 4; ++j) {
            const int c = n0 + wn * 64 + j * 16 + lr;
            const float bv_ = bias[c];
            #pragma unroll
            for (int e = 0; e < 4; ++e) {
                const int r = m0 + wm * 64 + i * 16 + lh * 4 + e;
                const float val = (acc[i][j][e] + bv_) * scale;
                const int b = r >> 11, t = r & 2047;
                const int h = c >> 6,  d = c & 63;
                size_t idx;
                if (seg == 2)      idx = ((size_t)(b * NHEADS + h) * HDIM + d) * T_SEQ + (t ^ ((d & 7) << 3));
                else if (seg == 1) idx = ((size_t)(b * NHEADS + h) * T_SEQ + t) * HDIM + (d ^ ((t & 7) << 3));
                else               idx = ((size_t)(b * NHEADS + h) * T_SEQ + t) * HDIM + d;
                outp[idx] = f2b(val);
            }
        }
    }
}

// ---- output GEMM: grid (64, 8), fp32 out ----
__global__ __launch_bounds__(256, 2) void out_gemm(
    const ushortT* __restrict__ A, const ushortT* __restrict__ Bw,
    const float* __restrict__ bias, float* __restrict__ outp)
{
    __shared__ __attribute__((aligned(16))) ushortT As[2][128 * 64];
    __shared__ __attribute__((aligned(16))) ushortT Bs[2][128 * 64];

    const int m0 = blockIdx.x * 128, n0 = blockIdx.y * 128;

    GEMM_PREAMBLE();
    GEMM_KLOOP();

    #pragma unroll
    for (int i = 0; i < 4; ++i) {
        #pragma unroll
        for (int j = 0; j < 4; ++j) {
            const int c = n0 + wn * 64 + j * 16 + lr;
            const float bv_ = bias[c];
            #pragma unroll
            for (int e = 0; e < 4; ++e) {
                const int r = m0 + wm * 64 + i * 16 + lh * 4 + e;
                outp[(size_t)r * 1024 + c] = acc[i][j][e] + bv_;
            }
        }
    }
}

// ---------------- flash attention, causal, swapped-operand softmax ----------------
// Q pre-scaled by QSCALE (log2 domain). K: (BH,T,64) swizzled d^=(t&7)<<3.
// Vt: (BH,64,T) swizzled t^=(d&7)<<3.  Ob out: (B,T,D) bf16 swizzled c^=(t&7)<<3.
__global__ __launch_bounds__(256, 4) void attn_fwd(
    const ushortT* __restrict__ Qb, const ushortT* __restrict__ Kb,
    const ushortT* __restrict__ Vt, ushortT* __restrict__ Ob)
{
    __shared__ __attribute__((aligned(16))) ushortT Ks[2][64 * 64];
    __shared__ __attribute__((aligned(16))) ushortT Vs[2][64 * 64];
    __shared__ __attribute__((aligned(16))) ushortT Ps[4][16 * 64];

    const int tid = threadIdx.x;
    const int w = tid >> 6, lane = tid & 63;
    const int lr = lane & 15, lh = lane >> 4;

    const int blk = blockIdx.x;
    const int j   = blk >> 3;
    const int bh  = (blk & 7) * 8 + (j >> 5);
    const int qt  = 31 - (j & 31);
    const int q0  = qt * 64;

    // Q fragments: B-operand (col=q=lane&15) for swapped QK^T
    const ushortT* qrow = Qb + ((size_t)bh * T_SEQ + q0 + w * 16 + lr) * HDIM;
    const s16x8 qf0 = *(const s16x8*)(qrow + lh * 8);
    const s16x8 qf1 = *(const s16x8*)(qrow + 32 + lh * 8);

    float m_r = -1e30f, l_r = 0.f;
    f32x4 o[4] = {};   // O^T: col=q=lr, row=d=ni*16+lh*4+e

    const int srow = tid >> 3;
    const int sk   = (tid & 7) * 8;

    const ushortT* Kbh = Kb + (size_t)bh * T_SEQ * HDIM;
    const ushortT* Vbh = Vt + (size_t)bh * HDIM * T_SEQ;

    #define STAGE(buf, kt_) do { \
        const int k0_ = (kt_) * 64; \
        const ushortT* kg = Kbh + (size_t)(k0_ + srow) * HDIM + sk; \
        const ushortT* vg = Vbh + (size_t)srow * T_SEQ + k0_ + sk; \
        __builtin_amdgcn_global_load_lds(GP(kg),                 LP(&Ks[buf][srow * 64 + sk]),        16, 0, 0); \
        __builtin_amdgcn_global_load_lds(GP(kg + 32 * HDIM),     LP(&Ks[buf][(32 + srow) * 64 + sk]), 16, 0, 0); \
        __builtin_amdgcn_global_load_lds(GP(vg),                 LP(&Vs[buf][srow * 64 + sk]),        16, 0, 0); \
        __builtin_amdgcn_global_load_lds(GP(vg + 32 * T_SEQ),    LP(&Vs[buf][(32 + srow) * 64 + sk]), 16, 0, 0); \
    } while (0)

    STAGE(0, 0);
    __syncthreads();

    const int g0 = (lh       ^ (lr & 7)) * 8;
    const int g1 = ((4 + lh) ^ (lr & 7)) * 8;

    for (int kt = 0; kt <= qt; ++kt) {
        const int cur = kt & 1;
        if (kt < qt) STAGE(cur ^ 1, kt + 1);

        // S^T = K Q^T: A=K-frag, B=Q-frag.  s[ni][e] = S[q=w*16+lr][kv=ni*16+lh*4+e]
        f32x4 s[4];
        __builtin_amdgcn_s_setprio(1);
        #pragma unroll
        for (int ni = 0; ni < 4; ++ni) {
            const int rr = ni * 16 + lr;
            s16x8 b0 = *(const s16x8*)&Ks[cur][rr * 64 + g0];
            s16x8 b1 = *(const s16x8*)&Ks[cur][rr * 64 + g1];
            f32x4 t = {};
            t = __builtin_amdgcn_mfma_f32_16x16x32_bf16(b0, qf0, t, 0, 0, 0);
            t = __builtin_amdgcn_mfma_f32_16x16x32_bf16(b1, qf1, t, 0, 0, 0);
            s[ni] = t;
        }
        __builtin_amdgcn_s_setprio(0);

        if (kt == qt) {   // diagonal tile: mask kv > q
            #pragma unroll
            for (int ni = 0; ni < 4; ++ni)
                #pragma unroll
                for (int e = 0; e < 4; ++e)
                    if (ni * 16 + lh * 4 + e > w * 16 + lr) s[ni][e] = -1e30f;
        }

        // per-lane row max (pairwise tree, max3-fusable) + 2 shfl to combine lh groups
        float pm;
        {
            float a0 = fmaxf(fmaxf(s[0][0], s[0][1]), fmaxf(s[0][2], s[0][3]));
            float a1 = fmaxf(fmaxf(s[1][0], s[1][1]), fmaxf(s[1][2], s[1][3]));
            float a2 = fmaxf(fmaxf(s[2][0], s[2][1]), fmaxf(s[2][2], s[2][3]));
            float a3 = fmaxf(fmaxf(s[3][0], s[3][1]), fmaxf(s[3][2], s[3][3]));
            pm = fmaxf(fmaxf(a0, a1), fmaxf(a2, a3));
        }
        pm = fmaxf(pm, __shfl_xor(pm, 16, 64));
        pm = fmaxf(pm, __shfl_xor(pm, 32, 64));

        // T13 defer-max: only rescale when some row grew by >8 (log2 domain; P <= 2^8)
        if (!__all(pm - m_r <= 8.f)) {
            const float mn = fmaxf(m_r, pm);
            const float sc = exp2f(m_r - mn);
            l_r *= sc;
            #pragma unroll
            for (int ni = 0; ni < 4; ++ni) o[ni] *= sc;
            m_r = mn;
        }

        float rs = 0.f;
        #pragma unroll
        for (int ni = 0; ni < 4; ++ni)
            #pragma unroll
            for (int e = 0; e < 4; ++e) {
                const float p = exp2f(s[ni][e] - m_r);
                s[ni][e] = p;
                rs += p;
            }
        rs += __shfl_xor(rs, 16, 64);
        rs += __shfl_xor(rs, 32, 64);
        l_r += rs;

        // P -> LDS: lane owns (q=lr, kv=ni*16+lh*4+e); hw cvt_pk + 8B stores, swizzled by (q&7)
        #pragma unroll
        for (int ni = 0; ni < 4; ++ni) {
            const unsigned u0 = cvtpk(s[ni][0], s[ni][1]);
            const unsigned u1 = cvtpk(s[ni][2], s[ni][3]);
            *(uint2*)&Ps[w][lr * 64 + ((ni * 16 + lh * 4) ^ ((lr & 7) << 3))] = make_uint2(u0, u1);
        }
        __asm__ volatile("s_waitcnt lgkmcnt(0)" ::: "memory");
        __builtin_amdgcn_sched_barrier(0);
        const s16x8 pf0 = *(const s16x8*)&Ps[w][lr * 64 + g0];   // P^T B-frag: col=q=lr, k=kv
        const s16x8 pf1 = *(const s16x8*)&Ps[w][lr * 64 + g1];

        // O^T += V^T P^T: A=V^T-frag, B=P^T-frag
        __builtin_amdgcn_s_setprio(1);
        #pragma unroll
        for (int ni = 0; ni < 4; ++ni) {
            const int dd = ni * 16 + lr;
            s16x8 v0 = *(const s16x8*)&Vs[cur][dd * 64 + g0];
            s16x8 v1 = *(const s16x8*)&Vs[cur][dd * 64 + g1];
            o[ni] = __builtin_amdgcn_mfma_f32_16x16x32_bf16(v0, pf0, o[ni], 0, 0, 0);
            o[ni] = __builtin_amdgcn_mfma_f32_16x16x32_bf16(v1, pf1, o[ni], 0, 0, 0);
        }
        __builtin_amdgcn_s_setprio(0);
        __syncthreads();
    }

    // epilogue: lane owns q-row t=q0+w*16+lr, d=ni*16+lh*4+e; cvt_pk + 8B stores, col-swizzled
    const int b = bh >> 4, h = bh & 15;
    const int t = q0 + w * 16 + lr;
    const float inv = 1.f / l_r;
    const size_t base = ((size_t)(b * T_SEQ) + t) * D_MODEL;
    #pragma unroll
    for (int ni = 0; ni < 4; ++ni) {
        const unsigned u0 = cvtpk(o[ni][0] * inv, o[ni][1] * inv);
        const unsigned u1 = cvtpk(o[ni][2] * inv, o[ni][3] * inv);
        const int c = h * HDIM + ni * 16 + lh * 4;
        *(uint2*)&Ob[base + (c ^ ((t & 7) << 3))] = make_uint2(u0, u1);
    }
}

extern "C" void kernel_launch(void* const* d_in, const int* in_sizes, int n_in,
                              void* d_out, int out_size, void* d_ws, size_t ws_size,
                              hipStream_t stream) {
    const float* x  = (const float*)d_in[0];
    const float* Wq = (const float*)d_in[1];
    const float* bq = (const float*)d_in[2];
    const float* Wk = (const float*)d_in[3];
    const float* bk = (const float*)d_in[4];
    const float* Wv = (const float*)d_in[5];
    const float* bv = (const float*)d_in[6];
    const float* Wo = (const float*)d_in[7];
    const float* bo = (const float*)d_in[8];

    ushortT* xb  = (ushortT*)d_ws;                    // swizzled bf16 copies (contiguous)
    ushortT* Wqb = xb  + (size_t)M_ROWS * D_MODEL;
    ushortT* Wkb = Wqb + (size_t)D_MODEL * D_MODEL;
    ushortT* Wvb = Wkb + (size_t)D_MODEL * D_MODEL;
    ushortT* Wob = Wvb + (size_t)D_MODEL * D_MODEL;
    ushortT* Qb  = Wob + (size_t)D_MODEL * D_MODEL;   // (BH,T,64) plain, log2-scaled
    ushortT* Kb  = Qb  + (size_t)M_ROWS * D_MODEL;    // (BH,T,64) swizzled
    ushortT* Vtb = Kb  + (size_t)M_ROWS * D_MODEL;    // (BH,64,T) swizzled
    ushortT* Ob  = Vtb + (size_t)M_ROWS * D_MODEL;    // (B,T,D)  swizzled

    cast_all<<<6144, 256, 0, stream>>>(x, Wq, Wk, Wv, Wo, xb);

    qkv_gemm<<<dim3(64, 24), 256, 0, stream>>>(xb, Wqb, Wkb, Wvb, bq, bk, bv, Qb, Kb, Vtb);

    attn_fwd<<<2048, 256, 0, stream>>>(Qb, Kb, Vtb, Ob);

    out_gemm<<<dim3(64, 8), 256, 0, stream>>>(Ob, Wob, bo, (float*)d_out);
}

// Round 7
// 273.557 us; speedup vs baseline: 1.8211x; 1.0830x over previous
//
#include <hip/hip_runtime.h>
#include <hip/hip_bf16.h>

#define D_MODEL 1024
#define T_SEQ   2048
#define BATCH   4
#define NHEADS  16
#define HDIM    64
#define M_ROWS  (BATCH * T_SEQ)   // 8192
#define QSCALE  (0.125f * 1.44269504088896340736f)   // 1/sqrt(64) * log2(e)

typedef unsigned short ushortT;
typedef __attribute__((ext_vector_type(4))) float f32x4;
typedef __attribute__((ext_vector_type(8))) short s16x8;

#define GP(p) ((const __attribute__((address_space(1))) void*)(p))
#define LP(p) ((__attribute__((address_space(3))) void*)(p))

static __device__ __forceinline__ ushortT f2b(float f) {
    union { float f; unsigned u; } v; v.f = f;
    unsigned r = v.u + 0x7fffu + ((v.u >> 16) & 1u);
    return (ushortT)(r >> 16);
}

// packed f32x2 -> bf16x2 (hardware cvt, S0->low, S1->high)
static __device__ __forceinline__ unsigned cvtpk(float lo, float hi) {
    unsigned r;
    asm("v_cvt_pk_bf16_f32 %0, %1, %2" : "=v"(r) : "v"(lo), "v"(hi));
    return r;
}

// ---- fused cast: x + 4 weights, fp32 -> bf16, XOR-swizzled by (row&7) ----
__global__ void cast_all(const float* __restrict__ x,
                         const float* __restrict__ Wq, const float* __restrict__ Wk,
                         const float* __restrict__ Wv, const float* __restrict__ Wo,
                         ushortT* __restrict__ dst) {
    const int i = blockIdx.x * 256 + threadIdx.x;
    const float* src; int g, ob;
    if (i < 1048576)      { src = x;  g = i;           ob = 0; }
    else if (i < 1179648) { src = Wq; g = i - 1048576; ob = 1048576; }
    else if (i < 1310720) { src = Wk; g = i - 1179648; ob = 1179648; }
    else if (i < 1441792) { src = Wv; g = i - 1310720; ob = 1310720; }
    else                  { src = Wo; g = i - 1441792; ob = 1441792; }
    const float4* s = (const float4*)src;
    float4 a = s[g * 2], b = s[g * 2 + 1];
    s16x8 r;
    r[0] = f2b(a.x); r[1] = f2b(a.y); r[2] = f2b(a.z); r[3] = f2b(a.w);
    r[4] = f2b(b.x); r[5] = f2b(b.y); r[6] = f2b(b.z); r[7] = f2b(b.w);
    ((s16x8*)dst)[ob + (g ^ ((g >> 7) & 7))] = r;
}

// ================= shared GEMM machinery (2-phase, double-buffered) =================
// A and Bw stored granule-swizzled: elem[m][k ^ ((m&7)<<3)].
// 128x128 tile, BK=64, 4 waves (2x2), 16 K-steps.

#define GEMM_PREAMBLE()                                                  \
    const int tid  = threadIdx.x;                                        \
    const int wave = tid >> 6, lane = tid & 63;                          \
    const int wm = wave >> 1, wn = wave & 1;                             \
    const int lr = lane & 15, lh = lane >> 4;                            \
    const int srow = tid >> 3;                                           \
    const int sg   = tid & 7;                                            \
    f32x4 acc[4][4] = {};                                                \
    const ushortT* Ag = A  + (size_t)(m0 + srow) * 1024 + sg * 8;        \
    const ushortT* Bg = Bw + (size_t)(n0 + srow) * 1024 + sg * 8;

#define STAGE_G(buf, k0)                                                               \
    do {                                                                               \
        _Pragma("unroll")                                                              \
        for (int is = 0; is < 4; ++is) {                                               \
            __builtin_amdgcn_global_load_lds(GP(Ag + (size_t)(is * 32) * 1024 + (k0)), \
                                             LP(&As[buf][is * 2048 + tid * 8]), 16, 0, 0); \
            __builtin_amdgcn_global_load_lds(GP(Bg + (size_t)(is * 32) * 1024 + (k0)), \
                                             LP(&Bs[buf][is * 2048 + tid * 8]), 16, 0, 0); \
        }                                                                              \
    } while (0)

#define COMPUTE_G(buf)                                                                 \
    do {                                                                               \
        _Pragma("unroll")                                                              \
        for (int kk = 0; kk < 2; ++kk) {                                               \
            s16x8 af[4], bfr[4];                                                       \
            const int g = ((kk * 4 + lh) ^ (lr & 7)) * 8;                              \
            _Pragma("unroll")                                                          \
            for (int i = 0; i < 4; ++i)                                                \
                af[i] = *(const s16x8*)&As[buf][(wm * 64 + i * 16 + lr) * 64 + g];     \
            _Pragma("unroll")                                                          \
            for (int j = 0; j < 4; ++j)                                                \
                bfr[j] = *(const s16x8*)&Bs[buf][(wn * 64 + j * 16 + lr) * 64 + g];    \
            __builtin_amdgcn_s_setprio(1);                                             \
            _Pragma("unroll")                                                          \
            for (int i = 0; i < 4; ++i)                                                \
                _Pragma("unroll")                                                      \
                for (int j = 0; j < 4; ++j)                                            \
                    acc[i][j] = __builtin_amdgcn_mfma_f32_16x16x32_bf16(af[i], bfr[j], acc[i][j], 0, 0, 0); \
            __builtin_amdgcn_s_setprio(0);                                             \
        }                                                                              \
    } while (0)

#define GEMM_KLOOP()                        \
    STAGE_G(0, 0);                          \
    __syncthreads();                        \
    for (int t = 0; t < 15; ++t) {          \
        const int cur = t & 1;              \
        STAGE_G(cur ^ 1, (t + 1) * 64);     \
        COMPUTE_G(cur);                     \
        __syncthreads();                    \
    }                                       \
    COMPUTE_G(1);

// ---- fused QKV GEMM: grid (64, 24); seg = y>>3 (0=Q,1=K,2=V) ----
__global__ __launch_bounds__(256, 2) void qkv_gemm(
    const ushortT* __restrict__ A,
    const ushortT* __restrict__ Wq, const ushortT* __restrict__ Wk, const ushortT* __restrict__ Wv,
    const float* __restrict__ bq, const float* __restrict__ bk, const float* __restrict__ bv,
    ushortT* __restrict__ Qb, ushortT* __restrict__ Kb, ushortT* __restrict__ Vtb)
{
    __shared__ __attribute__((aligned(16))) ushortT As[2][128 * 64];
    __shared__ __attribute__((aligned(16))) ushortT Bs[2][128 * 64];

    const int seg = blockIdx.y >> 3;
    const int m0 = blockIdx.x * 128, n0 = (blockIdx.y & 7) * 128;
    const ushortT* Bw   = (seg == 0) ? Wq : (seg == 1) ? Wk : Wv;
    const float*   bias = (seg == 0) ? bq : (seg == 1) ? bk : bv;
    const float    scale = (seg == 0) ? QSCALE : 1.0f;

    GEMM_PREAMBLE();
    GEMM_KLOOP();

    ushortT* outp = (seg == 0) ? Qb : (seg == 1) ? Kb : Vtb;
    #pragma unroll
    for (int i = 0; i < 4; ++i) {
        #pragma unroll
        for (int j = 0; j < 4; ++j) {
            const int c = n0 + wn * 64 + j * 16 + lr;
            const float bv_ = bias[c];
            #pragma unroll
            for (int e = 0; e < 4; ++e) {
                const int r = m0 + wm * 64 + i * 16 + lh * 4 + e;
                const float val = (acc[i][j][e] + bv_) * scale;
                const int b = r >> 11, t = r & 2047;
                const int h = c >> 6,  d = c & 63;
                size_t idx;
                if (seg == 2)      idx = ((size_t)(b * NHEADS + h) * HDIM + d) * T_SEQ + (t ^ ((d & 7) << 3));
                else if (seg == 1) idx = ((size_t)(b * NHEADS + h) * T_SEQ + t) * HDIM + (d ^ ((t & 7) << 3));
                else               idx = ((size_t)(b * NHEADS + h) * T_SEQ + t) * HDIM + d;
                outp[idx] = f2b(val);
            }
        }
    }
}

// ---- output GEMM: grid (64, 8), fp32 out ----
__global__ __launch_bounds__(256, 2) void out_gemm(
    const ushortT* __restrict__ A, const ushortT* __restrict__ Bw,
    const float* __restrict__ bias, float* __restrict__ outp)
{
    __shared__ __attribute__((aligned(16))) ushortT As[2][128 * 64];
    __shared__ __attribute__((aligned(16))) ushortT Bs[2][128 * 64];

    const int m0 = blockIdx.x * 128, n0 = blockIdx.y * 128;

    GEMM_PREAMBLE();
    GEMM_KLOOP();

    #pragma unroll
    for (int i = 0; i < 4; ++i) {
        #pragma unroll
        for (int j = 0; j < 4; ++j) {
            const int c = n0 + wn * 64 + j * 16 + lr;
            const float bv_ = bias[c];
            #pragma unroll
            for (int e = 0; e < 4; ++e) {
                const int r = m0 + wm * 64 + i * 16 + lh * 4 + e;
                outp[(size_t)r * 1024 + c] = acc[i][j][e] + bv_;
            }
        }
    }
}

// ---------------- flash attention, causal, swapped-operand softmax ----------------
// PAIR-BALANCED grid: 1024 blocks; block handles q-tiles p and 31-p -> uniform 33
// KV-tile iterations per block; exactly one generation (256 CU x 4 blocks/CU).
// Q pre-scaled by QSCALE (log2 domain). K: (BH,T,64) swizzled d^=(t&7)<<3.
// Vt: (BH,64,T) swizzled t^=(d&7)<<3.  Ob out: (B,T,D) bf16 swizzled c^=(t&7)<<3.
__global__ __launch_bounds__(256, 4) void attn_fwd(
    const ushortT* __restrict__ Qb, const ushortT* __restrict__ Kb,
    const ushortT* __restrict__ Vt, ushortT* __restrict__ Ob)
{
    __shared__ __attribute__((aligned(16))) ushortT Ks[2][64 * 64];
    __shared__ __attribute__((aligned(16))) ushortT Vs[2][64 * 64];
    __shared__ __attribute__((aligned(16))) ushortT Ps[4][16 * 64];

    const int tid = threadIdx.x;
    const int w = tid >> 6, lane = tid & 63;
    const int lr = lane & 15, lh = lane >> 4;

    const int blk = blockIdx.x;
    const int bh  = (blk & 7) * 8 + ((blk >> 3) & 7);   // 8 heads per XCD
    const int p   = blk >> 6;                           // pair index 0..15

    const int srow = tid >> 3;
    const int sk   = (tid & 7) * 8;

    const ushortT* Kbh = Kb + (size_t)bh * T_SEQ * HDIM;
    const ushortT* Vbh = Vt + (size_t)bh * HDIM * T_SEQ;
    const int b = bh >> 4, h = bh & 15;

    const int g0 = (lh       ^ (lr & 7)) * 8;
    const int g1 = ((4 + lh) ^ (lr & 7)) * 8;

    #define STAGE(buf, kt_) do { \
        const int k0_ = (kt_) * 64; \
        const ushortT* kg = Kbh + (size_t)(k0_ + srow) * HDIM + sk; \
        const ushortT* vg = Vbh + (size_t)srow * T_SEQ + k0_ + sk; \
        __builtin_amdgcn_global_load_lds(GP(kg),                 LP(&Ks[buf][srow * 64 + sk]),        16, 0, 0); \
        __builtin_amdgcn_global_load_lds(GP(kg + 32 * HDIM),     LP(&Ks[buf][(32 + srow) * 64 + sk]), 16, 0, 0); \
        __builtin_amdgcn_global_load_lds(GP(vg),                 LP(&Vs[buf][srow * 64 + sk]),        16, 0, 0); \
        __builtin_amdgcn_global_load_lds(GP(vg + 32 * T_SEQ),    LP(&Vs[buf][(32 + srow) * 64 + sk]), 16, 0, 0); \
    } while (0)

    #pragma unroll 1
    for (int half = 0; half < 2; ++half) {
        const int qt = half ? (31 - p) : p;
        const int q0 = qt * 64;

        STAGE(0, 0);                         // prefetch KV tile 0 (overlaps Q loads)

        // Q fragments: B-operand (col=q=lane&15) for swapped QK^T
        const ushortT* qrow = Qb + ((size_t)bh * T_SEQ + q0 + w * 16 + lr) * HDIM;
        const s16x8 qf0 = *(const s16x8*)(qrow + lh * 8);
        const s16x8 qf1 = *(const s16x8*)(qrow + 32 + lh * 8);

        float m_r = -1e30f, l_r = 0.f;
        f32x4 o[4] = {};   // O^T: col=q=lr, row=d=ni*16+lh*4+e

        __syncthreads();

        for (int kt = 0; kt <= qt; ++kt) {
            const int cur = kt & 1;
            if (kt < qt) STAGE(cur ^ 1, kt + 1);

            // S^T = K Q^T: A=K-frag, B=Q-frag.  s[ni][e] = S[q=w*16+lr][kv=ni*16+lh*4+e]
            f32x4 s[4];
            __builtin_amdgcn_s_setprio(1);
            #pragma unroll
            for (int ni = 0; ni < 4; ++ni) {
                const int rr = ni * 16 + lr;
                s16x8 b0 = *(const s16x8*)&Ks[cur][rr * 64 + g0];
                s16x8 b1 = *(const s16x8*)&Ks[cur][rr * 64 + g1];
                f32x4 t = {};
                t = __builtin_amdgcn_mfma_f32_16x16x32_bf16(b0, qf0, t, 0, 0, 0);
                t = __builtin_amdgcn_mfma_f32_16x16x32_bf16(b1, qf1, t, 0, 0, 0);
                s[ni] = t;
            }
            __builtin_amdgcn_s_setprio(0);

            if (kt == qt) {   // diagonal tile: mask kv > q
                #pragma unroll
                for (int ni = 0; ni < 4; ++ni)
                    #pragma unroll
                    for (int e = 0; e < 4; ++e)
                        if (ni * 16 + lh * 4 + e > w * 16 + lr) s[ni][e] = -1e30f;
            }

            // per-lane row max (pairwise tree) + 2 shfl to combine lh groups
            float pm;
            {
                float a0 = fmaxf(fmaxf(s[0][0], s[0][1]), fmaxf(s[0][2], s[0][3]));
                float a1 = fmaxf(fmaxf(s[1][0], s[1][1]), fmaxf(s[1][2], s[1][3]));
                float a2 = fmaxf(fmaxf(s[2][0], s[2][1]), fmaxf(s[2][2], s[2][3]));
                float a3 = fmaxf(fmaxf(s[3][0], s[3][1]), fmaxf(s[3][2], s[3][3]));
                pm = fmaxf(fmaxf(a0, a1), fmaxf(a2, a3));
            }
            pm = fmaxf(pm, __shfl_xor(pm, 16, 64));
            pm = fmaxf(pm, __shfl_xor(pm, 32, 64));

            // T13 defer-max: only rescale when some row grew by >8 (log2 domain; P <= 2^8)
            if (!__all(pm - m_r <= 8.f)) {
                const float mn = fmaxf(m_r, pm);
                const float sc = exp2f(m_r - mn);
                l_r *= sc;
                #pragma unroll
                for (int ni = 0; ni < 4; ++ni) o[ni] *= sc;
                m_r = mn;
            }

            float rs = 0.f;
            #pragma unroll
            for (int ni = 0; ni < 4; ++ni)
                #pragma unroll
                for (int e = 0; e < 4; ++e) {
                    const float pv_ = exp2f(s[ni][e] - m_r);
                    s[ni][e] = pv_;
                    rs += pv_;
                }
            rs += __shfl_xor(rs, 16, 64);
            rs += __shfl_xor(rs, 32, 64);
            l_r += rs;

            // P -> LDS: lane owns (q=lr, kv=ni*16+lh*4+e); hw cvt_pk + 8B stores, swizzled
            #pragma unroll
            for (int ni = 0; ni < 4; ++ni) {
                const unsigned u0 = cvtpk(s[ni][0], s[ni][1]);
                const unsigned u1 = cvtpk(s[ni][2], s[ni][3]);
                *(uint2*)&Ps[w][lr * 64 + ((ni * 16 + lh * 4) ^ ((lr & 7) << 3))] = make_uint2(u0, u1);
            }
            __asm__ volatile("s_waitcnt lgkmcnt(0)" ::: "memory");
            __builtin_amdgcn_sched_barrier(0);
            const s16x8 pf0 = *(const s16x8*)&Ps[w][lr * 64 + g0];   // P^T B-frag
            const s16x8 pf1 = *(const s16x8*)&Ps[w][lr * 64 + g1];

            // O^T += V^T P^T: A=V^T-frag, B=P^T-frag
            __builtin_amdgcn_s_setprio(1);
            #pragma unroll
            for (int ni = 0; ni < 4; ++ni) {
                const int dd = ni * 16 + lr;
                s16x8 v0 = *(const s16x8*)&Vs[cur][dd * 64 + g0];
                s16x8 v1 = *(const s16x8*)&Vs[cur][dd * 64 + g1];
                o[ni] = __builtin_amdgcn_mfma_f32_16x16x32_bf16(v0, pf0, o[ni], 0, 0, 0);
                o[ni] = __builtin_amdgcn_mfma_f32_16x16x32_bf16(v1, pf1, o[ni], 0, 0, 0);
            }
            __builtin_amdgcn_s_setprio(0);
            __syncthreads();
        }

        // epilogue: lane owns q-row t=q0+w*16+lr, d=ni*16+lh*4+e; cvt_pk + 8B stores
        const int t = q0 + w * 16 + lr;
        const float inv = 1.f / l_r;
        const size_t base = ((size_t)(b * T_SEQ) + t) * D_MODEL;
        #pragma unroll
        for (int ni = 0; ni < 4; ++ni) {
            const unsigned u0 = cvtpk(o[ni][0] * inv, o[ni][1] * inv);
            const unsigned u1 = cvtpk(o[ni][2] * inv, o[ni][3] * inv);
            const int c = h * HDIM + ni * 16 + lh * 4;
            *(uint2*)&Ob[base + (c ^ ((t & 7) << 3))] = make_uint2(u0, u1);
        }
    }
}

extern "C" void kernel_launch(void* const* d_in, const int* in_sizes, int n_in,
                              void* d_out, int out_size, void* d_ws, size_t ws_size,
                              hipStream_t stream) {
    const float* x  = (const float*)d_in[0];
    const float* Wq = (const float*)d_in[1];
    const float* bq = (const float*)d_in[2];
    const float* Wk = (const float*)d_in[3];
    const float* bk = (const float*)d_in[4];
    const float* Wv = (const float*)d_in[5];
    const float* bv = (const float*)d_in[6];
    const float* Wo = (const float*)d_in[7];
    const float* bo = (const float*)d_in[8];

    ushortT* xb  = (ushortT*)d_ws;                    // swizzled bf16 copies (contiguous)
    ushortT* Wqb = xb  + (size_t)M_ROWS * D_MODEL;
    ushortT* Wkb = Wqb + (size_t)D_MODEL * D_MODEL;
    ushortT* Wvb = Wkb + (size_t)D_MODEL * D_MODEL;
    ushortT* Wob = Wvb + (size_t)D_MODEL * D_MODEL;
    ushortT* Qb  = Wob + (size_t)D_MODEL * D_MODEL;   // (BH,T,64) plain, log2-scaled
    ushortT* Kb  = Qb  + (size_t)M_ROWS * D_MODEL;    // (BH,T,64) swizzled
    ushortT* Vtb = Kb  + (size_t)M_ROWS * D_MODEL;    // (BH,64,T) swizzled
    ushortT* Ob  = Vtb + (size_t)M_ROWS * D_MODEL;    // (B,T,D)  swizzled

    cast_all<<<6144, 256, 0, stream>>>(x, Wq, Wk, Wv, Wo, xb);

    qkv_gemm<<<dim3(64, 24), 256, 0, stream>>>(xb, Wqb, Wkb, Wvb, bq, bk, bv, Qb, Kb, Vtb);

    attn_fwd<<<1024, 256, 0, stream>>>(Qb, Kb, Vtb, Ob);

    out_gemm<<<dim3(64, 8), 256, 0, stream>>>(Ob, Wob, bo, (float*)d_out);
}

// Round 8
// 270.823 us; speedup vs baseline: 1.8395x; 1.0101x over previous
//
#include <hip/hip_runtime.h>
#include <hip/hip_bf16.h>

#define D_MODEL 1024
#define T_SEQ   2048
#define BATCH   4
#define NHEADS  16
#define HDIM    64
#define M_ROWS  (BATCH * T_SEQ)   // 8192
#define QSCALE  (0.125f * 1.44269504088896340736f)   // 1/sqrt(64) * log2(e)

typedef unsigned short ushortT;
typedef __attribute__((ext_vector_type(4))) float f32x4;
typedef __attribute__((ext_vector_type(8))) short s16x8;

#define GP(p) ((const __attribute__((address_space(1))) void*)(p))
#define LP(p) ((__attribute__((address_space(3))) void*)(p))

static __device__ __forceinline__ ushortT f2b(float f) {
    union { float f; unsigned u; } v; v.f = f;
    unsigned r = v.u + 0x7fffu + ((v.u >> 16) & 1u);
    return (ushortT)(r >> 16);
}

// packed f32x2 -> bf16x2 (hardware cvt, S0->low, S1->high)
static __device__ __forceinline__ unsigned cvtpk(float lo, float hi) {
    unsigned r;
    asm("v_cvt_pk_bf16_f32 %0, %1, %2" : "=v"(r) : "v"(lo), "v"(hi));
    return r;
}

// ---- fused cast: x + 4 weights, fp32 -> bf16, XOR-swizzled by (row&7) ----
__global__ void cast_all(const float* __restrict__ x,
                         const float* __restrict__ Wq, const float* __restrict__ Wk,
                         const float* __restrict__ Wv, const float* __restrict__ Wo,
                         ushortT* __restrict__ dst) {
    const int i = blockIdx.x * 256 + threadIdx.x;
    const float* src; int g, ob;
    if (i < 1048576)      { src = x;  g = i;           ob = 0; }
    else if (i < 1179648) { src = Wq; g = i - 1048576; ob = 1048576; }
    else if (i < 1310720) { src = Wk; g = i - 1179648; ob = 1179648; }
    else if (i < 1441792) { src = Wv; g = i - 1310720; ob = 1310720; }
    else                  { src = Wo; g = i - 1441792; ob = 1441792; }
    const float4* s = (const float4*)src;
    float4 a = s[g * 2], b = s[g * 2 + 1];
    s16x8 r;
    r[0] = f2b(a.x); r[1] = f2b(a.y); r[2] = f2b(a.z); r[3] = f2b(a.w);
    r[4] = f2b(b.x); r[5] = f2b(b.y); r[6] = f2b(b.z); r[7] = f2b(b.w);
    ((s16x8*)dst)[ob + (g ^ ((g >> 7) & 7))] = r;
}

// ================= shared GEMM machinery (2-phase, double-buffered) =================
// A and Bw stored granule-swizzled: elem[m][k ^ ((m&7)<<3)].
// 128x128 tile, BK=64, 4 waves (2x2), 16 K-steps.

#define GEMM_PREAMBLE()                                                  \
    const int tid  = threadIdx.x;                                        \
    const int wave = tid >> 6, lane = tid & 63;                          \
    const int wm = wave >> 1, wn = wave & 1;                             \
    const int lr = lane & 15, lh = lane >> 4;                            \
    const int srow = tid >> 3;                                           \
    const int sg   = tid & 7;                                            \
    f32x4 acc[4][4] = {};                                                \
    const ushortT* Ag = A  + (size_t)(m0 + srow) * 1024 + sg * 8;        \
    const ushortT* Bg = Bw + (size_t)(n0 + srow) * 1024 + sg * 8;

#define STAGE_G(buf, k0)                                                               \
    do {                                                                               \
        _Pragma("unroll")                                                              \
        for (int is = 0; is < 4; ++is) {                                               \
            __builtin_amdgcn_global_load_lds(GP(Ag + (size_t)(is * 32) * 1024 + (k0)), \
                                             LP(&As[buf][is * 2048 + tid * 8]), 16, 0, 0); \
            __builtin_amdgcn_global_load_lds(GP(Bg + (size_t)(is * 32) * 1024 + (k0)), \
                                             LP(&Bs[buf][is * 2048 + tid * 8]), 16, 0, 0); \
        }                                                                              \
    } while (0)

#define COMPUTE_G(buf)                                                                 \
    do {                                                                               \
        _Pragma("unroll")                                                              \
        for (int kk = 0; kk < 2; ++kk) {                                               \
            s16x8 af[4], bfr[4];                                                       \
            const int g = ((kk * 4 + lh) ^ (lr & 7)) * 8;                              \
            _Pragma("unroll")                                                          \
            for (int i = 0; i < 4; ++i)                                                \
                af[i] = *(const s16x8*)&As[buf][(wm * 64 + i * 16 + lr) * 64 + g];     \
            _Pragma("unroll")                                                          \
            for (int j = 0; j < 4; ++j)                                                \
                bfr[j] = *(const s16x8*)&Bs[buf][(wn * 64 + j * 16 + lr) * 64 + g];    \
            __builtin_amdgcn_s_setprio(1);                                             \
            _Pragma("unroll")                                                          \
            for (int i = 0; i < 4; ++i)                                                \
                _Pragma("unroll")                                                      \
                for (int j = 0; j < 4; ++j)                                            \
                    acc[i][j] = __builtin_amdgcn_mfma_f32_16x16x32_bf16(af[i], bfr[j], acc[i][j], 0, 0, 0); \
            __builtin_amdgcn_s_setprio(0);                                             \
        }                                                                              \
    } while (0)

#define GEMM_KLOOP()                        \
    STAGE_G(0, 0);                          \
    __syncthreads();                        \
    for (int t = 0; t < 15; ++t) {          \
        const int cur = t & 1;              \
        STAGE_G(cur ^ 1, (t + 1) * 64);     \
        COMPUTE_G(cur);                     \
        __syncthreads();                    \
    }                                       \
    COMPUTE_G(1);

// ---- fused QKV GEMM: grid (64, 24); seg = y>>3 (0=Q,1=K,2=V) ----
__global__ __launch_bounds__(256, 2) void qkv_gemm(
    const ushortT* __restrict__ A,
    const ushortT* __restrict__ Wq, const ushortT* __restrict__ Wk, const ushortT* __restrict__ Wv,
    const float* __restrict__ bq, const float* __restrict__ bk, const float* __restrict__ bv,
    ushortT* __restrict__ Qb, ushortT* __restrict__ Kb, ushortT* __restrict__ Vtb)
{
    __shared__ __attribute__((aligned(16))) ushortT As[2][128 * 64];
    __shared__ __attribute__((aligned(16))) ushortT Bs[2][128 * 64];

    const int seg = blockIdx.y >> 3;
    const int m0 = blockIdx.x * 128, n0 = (blockIdx.y & 7) * 128;
    const ushortT* Bw   = (seg == 0) ? Wq : (seg == 1) ? Wk : Wv;
    const float*   bias = (seg == 0) ? bq : (seg == 1) ? bk : bv;
    const float    scale = (seg == 0) ? QSCALE : 1.0f;

    GEMM_PREAMBLE();
    GEMM_KLOOP();

    ushortT* outp = (seg == 0) ? Qb : (seg == 1) ? Kb : Vtb;
    #pragma unroll
    for (int i = 0; i < 4; ++i) {
        #pragma unroll
        for (int j = 0; j < 4; ++j) {
            const int c = n0 + wn * 64 + j * 16 + lr;
            const float bv_ = bias[c];
            #pragma unroll
            for (int e = 0; e < 4; ++e) {
                const int r = m0 + wm * 64 + i * 16 + lh * 4 + e;
                const float val = (acc[i][j][e] + bv_) * scale;
                const int b = r >> 11, t = r & 2047;
                const int h = c >> 6,  d = c & 63;
                size_t idx;
                if (seg == 2)      idx = ((size_t)(b * NHEADS + h) * HDIM + d) * T_SEQ + (t ^ ((d & 7) << 3));
                else if (seg == 1) idx = ((size_t)(b * NHEADS + h) * T_SEQ + t) * HDIM + (d ^ ((t & 7) << 3));
                else               idx = ((size_t)(b * NHEADS + h) * T_SEQ + t) * HDIM + d;
                outp[idx] = f2b(val);
            }
        }
    }
}

// ---- output GEMM: grid (64, 8), fp32 out ----
__global__ __launch_bounds__(256, 2) void out_gemm(
    const ushortT* __restrict__ A, const ushortT* __restrict__ Bw,
    const float* __restrict__ bias, float* __restrict__ outp)
{
    __shared__ __attribute__((aligned(16))) ushortT As[2][128 * 64];
    __shared__ __attribute__((aligned(16))) ushortT Bs[2][128 * 64];

    const int m0 = blockIdx.x * 128, n0 = blockIdx.y * 128;

    GEMM_PREAMBLE();
    GEMM_KLOOP();

    #pragma unroll
    for (int i = 0; i < 4; ++i) {
        #pragma unroll
        for (int j = 0; j < 4; ++j) {
            const int c = n0 + wn * 64 + j * 16 + lr;
            const float bv_ = bias[c];
            #pragma unroll
            for (int e = 0; e < 4; ++e) {
                const int r = m0 + wm * 64 + i * 16 + lh * 4 + e;
                outp[(size_t)r * 1024 + c] = acc[i][j][e] + bv_;
            }
        }
    }
}

// ---------------- flash attention, causal, swapped-operand softmax ----------------
// 8-wave blocks (512 thr), 128 q-rows/block sharing one K/V stream.
// Grid 1024 = 64 bh x 16 q-groups; LPT order (big qg first) + XCD head-grouping.
// LDS 48KB -> 3 blocks/CU = 24 waves/CU.
// Q pre-scaled by QSCALE (log2 domain). K: (BH,T,64) swizzled d^=(t&7)<<3.
// Vt: (BH,64,T) swizzled t^=(d&7)<<3.  Ob out: (B,T,D) bf16 swizzled c^=(t&7)<<3.
__global__ __launch_bounds__(512, 6) void attn_fwd(
    const ushortT* __restrict__ Qb, const ushortT* __restrict__ Kb,
    const ushortT* __restrict__ Vt, ushortT* __restrict__ Ob)
{
    __shared__ __attribute__((aligned(16))) ushortT Ks[2][64 * 64];
    __shared__ __attribute__((aligned(16))) ushortT Vs[2][64 * 64];
    __shared__ __attribute__((aligned(16))) ushortT Ps[8][16 * 64];

    const int tid = threadIdx.x;
    const int w = tid >> 6, lane = tid & 63;
    const int lr = lane & 15, lh = lane >> 4;

    const int blk  = blockIdx.x;
    const int bh   = (blk & 7) * 8 + ((blk >> 3) & 7);  // 8 heads per XCD
    const int grp  = blk >> 6;                          // 0..15
    const int qg64 = (15 - grp) * 2;                    // q-group start in 64-tiles (LPT)
    const int q0   = qg64 * 64;                         // q-group start row (multiple of 128)
    const int last = qg64 + 1;                          // last KV tile index

    const int srow = tid >> 3;       // 0..63
    const int sk   = (tid & 7) * 8;

    const ushortT* Kbh = Kb + (size_t)bh * T_SEQ * HDIM;
    const ushortT* Vbh = Vt + (size_t)bh * HDIM * T_SEQ;
    const int b = bh >> 4, h = bh & 15;

    const int g0 = (lh       ^ (lr & 7)) * 8;
    const int g1 = ((4 + lh) ^ (lr & 7)) * 8;

    // single-issue staging: 512 thr x 16B = 8KB = one 64x64 bf16 tile
    #define STAGE(buf, kt_) do { \
        const int k0_ = (kt_) * 64; \
        __builtin_amdgcn_global_load_lds(GP(Kbh + (size_t)(k0_ + srow) * HDIM + sk), \
                                         LP(&Ks[buf][srow * 64 + sk]), 16, 0, 0); \
        __builtin_amdgcn_global_load_lds(GP(Vbh + (size_t)srow * T_SEQ + k0_ + sk), \
                                         LP(&Vs[buf][srow * 64 + sk]), 16, 0, 0); \
    } while (0)

    STAGE(0, 0);

    // Q fragments: B-operand (col=q=lane&15) for swapped QK^T
    const ushortT* qrow = Qb + ((size_t)bh * T_SEQ + q0 + w * 16 + lr) * HDIM;
    const s16x8 qf0 = *(const s16x8*)(qrow + lh * 8);
    const s16x8 qf1 = *(const s16x8*)(qrow + 32 + lh * 8);

    float m_r = -1e30f, l_r = 0.f;
    f32x4 o[4] = {};   // O^T: col=q=lr, row=d=ni*16+lh*4+e

    const int dt = qg64 + (w >> 2);   // this wave's diagonal KV tile

    __syncthreads();

    for (int kt = 0; kt <= last; ++kt) {
        const int cur = kt & 1;
        if (kt < last) STAGE(cur ^ 1, kt + 1);

        if (kt <= dt) {   // skip fully-masked tiles (waves 0-3 at kt=last)
            // S^T = K Q^T: A=K-frag, B=Q-frag.  s[ni][e] = S[q][kv=ni*16+lh*4+e]
            f32x4 s[4];
            __builtin_amdgcn_s_setprio(1);
            #pragma unroll
            for (int ni = 0; ni < 4; ++ni) {
                const int rr = ni * 16 + lr;
                s16x8 b0 = *(const s16x8*)&Ks[cur][rr * 64 + g0];
                s16x8 b1 = *(const s16x8*)&Ks[cur][rr * 64 + g1];
                f32x4 t = {};
                t = __builtin_amdgcn_mfma_f32_16x16x32_bf16(b0, qf0, t, 0, 0, 0);
                t = __builtin_amdgcn_mfma_f32_16x16x32_bf16(b1, qf1, t, 0, 0, 0);
                s[ni] = t;
            }
            __builtin_amdgcn_s_setprio(0);

            if (kt == dt) {   // diagonal tile: mask kv > q (local offset (w&3)*16+lr)
                #pragma unroll
                for (int ni = 0; ni < 4; ++ni)
                    #pragma unroll
                    for (int e = 0; e < 4; ++e)
                        if (ni * 16 + lh * 4 + e > (w & 3) * 16 + lr) s[ni][e] = -1e30f;
            }

            // per-lane row max (pairwise tree) + 2 shfl to combine lh groups
            float pm;
            {
                float a0 = fmaxf(fmaxf(s[0][0], s[0][1]), fmaxf(s[0][2], s[0][3]));
                float a1 = fmaxf(fmaxf(s[1][0], s[1][1]), fmaxf(s[1][2], s[1][3]));
                float a2 = fmaxf(fmaxf(s[2][0], s[2][1]), fmaxf(s[2][2], s[2][3]));
                float a3 = fmaxf(fmaxf(s[3][0], s[3][1]), fmaxf(s[3][2], s[3][3]));
                pm = fmaxf(fmaxf(a0, a1), fmaxf(a2, a3));
            }
            pm = fmaxf(pm, __shfl_xor(pm, 16, 64));
            pm = fmaxf(pm, __shfl_xor(pm, 32, 64));

            // T13 defer-max: only rescale when some row grew by >8 (log2 domain)
            if (!__all(pm - m_r <= 8.f)) {
                const float mn = fmaxf(m_r, pm);
                const float sc = exp2f(m_r - mn);
                l_r *= sc;
                #pragma unroll
                for (int ni = 0; ni < 4; ++ni) o[ni] *= sc;
                m_r = mn;
            }

            float rs = 0.f;
            #pragma unroll
            for (int ni = 0; ni < 4; ++ni)
                #pragma unroll
                for (int e = 0; e < 4; ++e) {
                    const float pv_ = exp2f(s[ni][e] - m_r);
                    s[ni][e] = pv_;
                    rs += pv_;
                }
            rs += __shfl_xor(rs, 16, 64);
            rs += __shfl_xor(rs, 32, 64);
            l_r += rs;

            // P -> LDS: lane owns (q=lr, kv=ni*16+lh*4+e); cvt_pk + 8B stores, swizzled
            #pragma unroll
            for (int ni = 0; ni < 4; ++ni) {
                const unsigned u0 = cvtpk(s[ni][0], s[ni][1]);
                const unsigned u1 = cvtpk(s[ni][2], s[ni][3]);
                *(uint2*)&Ps[w][lr * 64 + ((ni * 16 + lh * 4) ^ ((lr & 7) << 3))] = make_uint2(u0, u1);
            }
            __asm__ volatile("s_waitcnt lgkmcnt(0)" ::: "memory");
            __builtin_amdgcn_sched_barrier(0);
            const s16x8 pf0 = *(const s16x8*)&Ps[w][lr * 64 + g0];   // P^T B-frag
            const s16x8 pf1 = *(const s16x8*)&Ps[w][lr * 64 + g1];

            // O^T += V^T P^T: A=V^T-frag, B=P^T-frag
            __builtin_amdgcn_s_setprio(1);
            #pragma unroll
            for (int ni = 0; ni < 4; ++ni) {
                const int dd = ni * 16 + lr;
                s16x8 v0 = *(const s16x8*)&Vs[cur][dd * 64 + g0];
                s16x8 v1 = *(const s16x8*)&Vs[cur][dd * 64 + g1];
                o[ni] = __builtin_amdgcn_mfma_f32_16x16x32_bf16(v0, pf0, o[ni], 0, 0, 0);
                o[ni] = __builtin_amdgcn_mfma_f32_16x16x32_bf16(v1, pf1, o[ni], 0, 0, 0);
            }
            __builtin_amdgcn_s_setprio(0);
        }
        __syncthreads();
    }

    // epilogue: lane owns q-row t=q0+w*16+lr, d=ni*16+lh*4+e; cvt_pk + 8B stores
    const int t = q0 + w * 16 + lr;
    const float inv = 1.f / l_r;
    const size_t base = ((size_t)(b * T_SEQ) + t) * D_MODEL;
    #pragma unroll
    for (int ni = 0; ni < 4; ++ni) {
        const unsigned u0 = cvtpk(o[ni][0] * inv, o[ni][1] * inv);
        const unsigned u1 = cvtpk(o[ni][2] * inv, o[ni][3] * inv);
        const int c = h * HDIM + ni * 16 + lh * 4;
        *(uint2*)&Ob[base + (c ^ ((t & 7) << 3))] = make_uint2(u0, u1);
    }
}

extern "C" void kernel_launch(void* const* d_in, const int* in_sizes, int n_in,
                              void* d_out, int out_size, void* d_ws, size_t ws_size,
                              hipStream_t stream) {
    const float* x  = (const float*)d_in[0];
    const float* Wq = (const float*)d_in[1];
    const float* bq = (const float*)d_in[2];
    const float* Wk = (const float*)d_in[3];
    const float* bk = (const float*)d_in[4];
    const float* Wv = (const float*)d_in[5];
    const float* bv = (const float*)d_in[6];
    const float* Wo = (const float*)d_in[7];
    const float* bo = (const float*)d_in[8];

    ushortT* xb  = (ushortT*)d_ws;                    // swizzled bf16 copies (contiguous)
    ushortT* Wqb = xb  + (size_t)M_ROWS * D_MODEL;
    ushortT* Wkb = Wqb + (size_t)D_MODEL * D_MODEL;
    ushortT* Wvb = Wkb + (size_t)D_MODEL * D_MODEL;
    ushortT* Wob = Wvb + (size_t)D_MODEL * D_MODEL;
    ushortT* Qb  = Wob + (size_t)D_MODEL * D_MODEL;   // (BH,T,64) plain, log2-scaled
    ushortT* Kb  = Qb  + (size_t)M_ROWS * D_MODEL;    // (BH,T,64) swizzled
    ushortT* Vtb = Kb  + (size_t)M_ROWS * D_MODEL;    // (BH,64,T) swizzled
    ushortT* Ob  = Vtb + (size_t)M_ROWS * D_MODEL;    // (B,T,D)  swizzled

    cast_all<<<6144, 256, 0, stream>>>(x, Wq, Wk, Wv, Wo, xb);

    qkv_gemm<<<dim3(64, 24), 256, 0, stream>>>(xb, Wqb, Wkb, Wvb, bq, bk, bv, Qb, Kb, Vtb);

    attn_fwd<<<1024, 512, 0, stream>>>(Qb, Kb, Vtb, Ob);

    out_gemm<<<dim3(64, 8), 256, 0, stream>>>(Ob, Wob, bo, (float*)d_out);
}